// Round 5
// baseline (637.637 us; speedup 1.0000x reference)
//
#include <hip/hip_runtime.h>
#include <hip/hip_bf16.h>
#include <math.h>

typedef float f32x4 __attribute__((ext_vector_type(4)));
typedef short bf16x8 __attribute__((ext_vector_type(8)));

#define NPAR 100000
#define NFIG 20000
#define NTAB 20000
#define NCIT 50000
#define NEDGE 200000
#define CAP 32
#define MPAD 100096   // 782*128
#define PFCAP 79

__device__ __forceinline__ unsigned short f2b(float f) {
    union { float f; unsigned u; } x; x.f = f;
    unsigned r = x.u + 0x7FFFu + ((x.u >> 16) & 1u);
    return (unsigned short)(r >> 16);
}
__device__ __forceinline__ float b2f(unsigned short b) {
    union { unsigned u; float f; } x; x.u = ((unsigned)b) << 16; return x.f;
}
__device__ __forceinline__ float fast_tanh(float x) {
    float e = __expf(2.f * x);
    return 1.f - 2.f * __builtin_amdgcn_rcpf(e + 1.f);
}
__device__ __forceinline__ void async_copy16(const unsigned short* g, unsigned short* l) {
    __builtin_amdgcn_global_load_lds(
        (const __attribute__((address_space(1))) unsigned int*)g,
        (__attribute__((address_space(3))) unsigned int*)l, 16, 0, 0);
}

// ---- 5 weight transposes in one launch: W [256,256] f32 (k,n) -> WT bf16 [n][k] ----
__global__ void k_transpose5(const float* __restrict__ W0, const float* __restrict__ W1,
                             const float* __restrict__ W2, const float* __restrict__ W3,
                             const float* __restrict__ W4, unsigned short* __restrict__ WT) {
    int b = blockIdx.x, which = b >> 8, k = b & 255, n = threadIdx.x;
    const float* W = which == 0 ? W0 : which == 1 ? W1 : which == 2 ? W2 : which == 3 ? W3 : W4;
    WT[(size_t)which * 65536 + n * 256 + k] = f2b(W[k * 256 + n]);
}

// ---- u = Wh_fig @ cls_w1, v = Wh_par @ cls_w2, Cpart ----
__global__ void k_precompute(const float* __restrict__ WhF, const float* __restrict__ bhF,
                             const float* __restrict__ WhP, const float* __restrict__ bhP,
                             const float* __restrict__ clsw, const float* __restrict__ clsb,
                             float* __restrict__ u, float* __restrict__ v, float* __restrict__ smallb) {
    int t = threadIdx.x;
    float su = 0.f, sv = 0.f;
    for (int j = 0; j < 128; ++j) {
        su += WhF[t * 128 + j] * clsw[j];
        sv += WhP[t * 128 + j] * clsw[128 + j];
    }
    u[t] = su; v[t] = sv;
    if (t == 0) {
        float c = clsb[0];
        for (int j = 0; j < 128; ++j) c += bhF[j] * clsw[j] + bhP[j] * clsw[128 + j];
        smallb[264] = c;
    }
}

// ---- merged projection GEMM + fused att epilogue ----
struct ProjPack {
    const float* X[4];
    const unsigned short* WT[4];
    const float* bias[4];
    unsigned short* H[4];
    const float* av[16];   // [ty*4+v]
    float* ov[16];
    int nrows[4];
    int bbase[4];
    int nv[4];
};
__global__ __launch_bounds__(512, 4) void k_gemm_proj(ProjPack p) {
    __shared__ __align__(16) unsigned short As[2][128 * 32];   // 16 KB
    __shared__ __align__(16) unsigned short Bs[2][256 * 32];   // 32 KB (reused as C half-tile)
    int bid = blockIdx.x;
    int ty = (bid >= p.bbase[1]) + (bid >= p.bbase[2]) + (bid >= p.bbase[3]);
    int m0 = (bid - p.bbase[ty]) * 128;
    const float* Xf = p.X[ty];
    const unsigned short* B = p.WT[ty];
    unsigned short* Hout = p.H[ty];
    int Nrows = p.nrows[ty];
    int nv = p.nv[ty];

    int t = threadIdx.x, l = t & 63, w = t >> 6;
    int wm = (w >> 2) * 64, wn = (w & 3) * 64;
    int lr = l & 15, hi = l >> 4;
    int arow = t >> 2, acol = t & 3;
    bool aok = (m0 + arow) < Nrows;
    const float* Arow = Xf + (size_t)(m0 + arow) * 256 + acol * 8;
    f32x4 acc[4][4] = {};
    float4 a4[2];

    // att a-vector fragments (l covers cols l*4..l*4+3)
    float avr[4][4] = {};
#pragma unroll
    for (int v = 0; v < 4; ++v) {
        if (v < nv) {
            const float* A = p.av[ty * 4 + v];
#pragma unroll
            for (int j = 0; j < 4; ++j) avr[v][j] = A[l * 4 + j];
        }
    }

    auto loadA = [&](int k0) {
        if (aok) {
            const float4* ptr = reinterpret_cast<const float4*>(Arow + k0);
            a4[0] = ptr[0]; a4[1] = ptr[1];
        } else {
            a4[0] = a4[1] = make_float4(0.f, 0.f, 0.f, 0.f);
        }
    };
    auto writeA = [&](int buf) {
        __align__(16) unsigned short tmp[8];
        tmp[0] = f2b(a4[0].x); tmp[1] = f2b(a4[0].y); tmp[2] = f2b(a4[0].z); tmp[3] = f2b(a4[0].w);
        tmp[4] = f2b(a4[1].x); tmp[5] = f2b(a4[1].y); tmp[6] = f2b(a4[1].z); tmp[7] = f2b(a4[1].w);
        *reinterpret_cast<uint4*>(&As[buf][arow * 32 + ((acol ^ (arow & 3)) * 8)]) =
            *reinterpret_cast<const uint4*>(tmp);
    };
    auto stageB = [&](int buf, int k0) {
#pragma unroll
        for (int i = 0; i < 2; ++i) {
            int rowb = w * 32 + i * 16;
            async_copy16(B + (size_t)(rowb + (l >> 2)) * 256 + k0 + (((l & 3) ^ ((l >> 2) & 3)) * 8),
                         &Bs[buf][rowb * 32]);
        }
    };

    loadA(0); stageB(0, 0); writeA(0);
    __syncthreads();
    int cur = 0;
    for (int ks = 0; ks < 8; ++ks) {
        if (ks < 7) { loadA((ks + 1) * 32); stageB(cur ^ 1, (ks + 1) * 32); }
        bf16x8 af[4], bfr[4];
#pragma unroll
        for (int mm = 0; mm < 4; ++mm)
            af[mm] = *reinterpret_cast<const bf16x8*>(&As[cur][(wm + mm * 16 + lr) * 32 + ((hi ^ (lr & 3)) * 8)]);
#pragma unroll
        for (int nn = 0; nn < 4; ++nn)
            bfr[nn] = *reinterpret_cast<const bf16x8*>(&Bs[cur][(wn + nn * 16 + lr) * 32 + ((hi ^ (lr & 3)) * 8)]);
#pragma unroll
        for (int mm = 0; mm < 4; ++mm)
#pragma unroll
            for (int nn = 0; nn < 4; ++nn)
                acc[mm][nn] = __builtin_amdgcn_mfma_f32_16x16x32_bf16(af[mm], bfr[nn], acc[mm][nn], 0, 0, 0);
        if (ks < 7) writeA(cur ^ 1);
        __syncthreads();
        cur ^= 1;
    }

    // epilogue: two 64-row halves through LDS (Bs space), coalesced store + fused att
    float bv[4];
#pragma unroll
    for (int nn = 0; nn < 4; ++nn) bv[nn] = p.bias[ty][wn + nn * 16 + lr];
    unsigned short* Cl = &Bs[0][0];
    for (int hf = 0; hf < 2; ++hf) {
        if ((w >> 2) == hf) {
#pragma unroll
            for (int mm = 0; mm < 4; ++mm)
#pragma unroll
                for (int nn = 0; nn < 4; ++nn) {
                    int col = wn + nn * 16 + lr;
                    int cb = col >> 3, ce = col & 7;
#pragma unroll
                    for (int r = 0; r < 4; ++r) {
                        int row = mm * 16 + hi * 4 + r;
                        Cl[row * 256 + ((cb ^ (row & 7)) * 8) + ce] = f2b(acc[mm][nn][r] + bv[nn]);
                    }
                }
        }
        __syncthreads();
        // coalesced store of 64 rows
        {
            int row = t >> 3;
            int g = m0 + hf * 64 + row;
            if (g < Nrows) {
                unsigned short* dst = Hout + (size_t)g * 256;
#pragma unroll
                for (int pp = 0; pp < 4; ++pp) {
                    int u = (t & 7) + pp * 8;
                    uint4 val = *reinterpret_cast<const uint4*>(&Cl[row * 256 + ((u ^ (row & 7)) * 8)]);
                    *reinterpret_cast<uint4*>(dst + u * 8) = val;
                }
            }
        }
        // fused att dots: wave w handles rows w*8..w*8+7
        for (int j = 0; j < 8; ++j) {
            int row = w * 8 + j;
            int g = m0 + hf * 64 + row;
            if (g >= Nrows) continue;
            ushort4 hv = *reinterpret_cast<const ushort4*>(
                &Cl[row * 256 + (((l >> 1) ^ (row & 7)) * 8) + (l & 1) * 4]);
            float h0 = b2f(hv.x), h1 = b2f(hv.y), h2 = b2f(hv.z), h3 = b2f(hv.w);
#pragma unroll
            for (int v = 0; v < 4; ++v) {
                if (v >= nv) break;
                float s = h0 * avr[v][0] + h1 * avr[v][1] + h2 * avr[v][2] + h3 * avr[v][3];
                s += __shfl_xor(s, 1); s += __shfl_xor(s, 2); s += __shfl_xor(s, 4);
                if ((l & 7) == 0) p.ov[ty * 4 + v][g * 8 + (l >> 3)] = s;
            }
        }
        __syncthreads();
    }
}

// ---- fused gather + kmean: block = 128-dst tile; r built in LDS, GEMM in place ----
__global__ __launch_bounds__(512, 2) void k_gather_kmean(
    const int* __restrict__ src, const int* __restrict__ count,
    const int* __restrict__ elist, const unsigned short* __restrict__ Hsrc,
    const float* __restrict__ as_, const float* __restrict__ ad_,
    const unsigned short* __restrict__ Bw, const float* __restrict__ kb,
    const float* __restrict__ v, float* __restrict__ ksum,
    float* __restrict__ gout) {
    __shared__ __align__(16) unsigned short Ar[128 * 256];     // 64 KB, swizzled
    __shared__ __align__(16) unsigned short Bs[2][256 * 32];   // 32 KB
    int t = threadIdx.x, l = t & 63, w = t >> 6;
    int m0 = blockIdx.x * 128;
    int lg = l & 15, gb = l & 48;

    auto stageB = [&](int buf, int k0) {
#pragma unroll
        for (int i = 0; i < 2; ++i) {
            int rowb = w * 32 + i * 16;
            async_copy16(Bw + (size_t)(rowb + (l >> 2)) * 256 + k0 + (((l & 3) ^ ((l >> 2) & 3)) * 8),
                         &Bs[buf][rowb * 32]);
        }
    };
    stageB(0, 0);   // B loads fly during gather

    float vr[16];
#pragma unroll
    for (int k = 0; k < 16; ++k) vr[k] = v[lg * 16 + k];

    // gather: 4 rounds, one dst per 16-lane group (4 concurrent dsts/wave)
    for (int j = 0; j < 4; ++j) {
        int ld = w * 16 + j * 4 + (l >> 4);
        int d = m0 + ld;
        bool valid = d < NPAR;
        int cnt = 0;
        if (valid) { cnt = count[d]; if (cnt > CAP) cnt = CAP; }
        int s1 = 0, s2 = 0;
        if (lg < cnt) s1 = src[elist[(size_t)d * CAP + lg]];
        if (lg + 16 < cnt) s2 = src[elist[(size_t)d * CAP + lg + 16]];
        float adh = valid ? ad_[d * 8 + (lg >> 1)] : 0.f;
        float ar[16];
#pragma unroll
        for (int k = 0; k < 16; ++k) ar[k] = 0.f;
        float den = 0.f;
        for (int i = 0; i < cnt; ++i) {
            int s = (i < 16) ? __shfl(s1, gb + i) : __shfl(s2, gb + i - 16);
            float al = as_[s * 8 + (lg >> 1)] + adh;
            al = al > 0.f ? al : 0.2f * al;
            float ex = __expf(al); den += ex;
            const uint4* hp = reinterpret_cast<const uint4*>(Hsrc + (size_t)s * 256 + lg * 16);
            uint4 hv0 = hp[0], hv1 = hp[1];
            unsigned wds[8] = { hv0.x, hv0.y, hv0.z, hv0.w, hv1.x, hv1.y, hv1.z, hv1.w };
#pragma unroll
            for (int k = 0; k < 8; ++k) {
                ar[k * 2]     += ex * b2f((unsigned short)(wds[k] & 0xffffu));
                ar[k * 2 + 1] += ex * b2f((unsigned short)(wds[k] >> 16));
            }
        }
        float inv = 1.f / (den + 1e-16f);
        float gs = 0.f;
        __align__(16) unsigned short ob[16];
#pragma unroll
        for (int k = 0; k < 16; ++k) {
            float r = fmaxf(ar[k] * inv, 0.f);
            gs += r * vr[k];
            ob[k] = f2b(r);
        }
        int u0 = (lg * 2) ^ (ld & 7), u1 = (lg * 2 + 1) ^ (ld & 7);
        *reinterpret_cast<uint4*>(&Ar[ld * 256 + u0 * 8]) = *reinterpret_cast<const uint4*>(ob);
        *reinterpret_cast<uint4*>(&Ar[ld * 256 + u1 * 8]) = *reinterpret_cast<const uint4*>(ob + 8);
        gs += __shfl_xor(gs, 1); gs += __shfl_xor(gs, 2); gs += __shfl_xor(gs, 4); gs += __shfl_xor(gs, 8);
        if (lg == 0 && valid) gout[d] = gs;
    }
    __syncthreads();

    // GEMM: A resident in Ar, B double-buffered
    int wm = (w >> 2) * 64, wn = (w & 3) * 64, lr = l & 15, hi = l >> 4;
    f32x4 acc[4][4] = {};
    int cur = 0;
    for (int ks = 0; ks < 8; ++ks) {
        if (ks < 7) stageB(cur ^ 1, (ks + 1) * 32);
        bf16x8 af[4], bfr[4];
#pragma unroll
        for (int mm = 0; mm < 4; ++mm) {
            int rr = wm + mm * 16 + lr;
            af[mm] = *reinterpret_cast<const bf16x8*>(&Ar[rr * 256 + (((ks * 4 + hi) ^ (lr & 7)) * 8)]);
        }
#pragma unroll
        for (int nn = 0; nn < 4; ++nn)
            bfr[nn] = *reinterpret_cast<const bf16x8*>(&Bs[cur][(wn + nn * 16 + lr) * 32 + ((hi ^ (lr & 3)) * 8)]);
#pragma unroll
        for (int mm = 0; mm < 4; ++mm)
#pragma unroll
            for (int nn = 0; nn < 4; ++nn)
                acc[mm][nn] = __builtin_amdgcn_mfma_f32_16x16x32_bf16(af[mm], bfr[nn], acc[mm][nn], 0, 0, 0);
        __syncthreads();
        cur ^= 1;
    }
#pragma unroll
    for (int nn = 0; nn < 4; ++nn) {
        int col = wn + nn * 16 + lr;
        float kbv = kb[col];
        float cs = 0.f;
#pragma unroll
        for (int mm = 0; mm < 4; ++mm)
#pragma unroll
            for (int r = 0; r < 4; ++r) {
                int row = m0 + wm + mm * 16 + hi * 4 + r;
                if (row < NPAR) cs += fast_tanh(acc[mm][nn][r] + kbv);
            }
        cs += __shfl_xor(cs, 16);
        cs += __shfl_xor(cs, 32);
        if (hi == 0) atomicAdd(&ksum[col], cs);
    }
}

// ---- bucket all 3 metapaths in one launch ----
__global__ void k_bucket3(const int* __restrict__ d0, const int* __restrict__ d1,
                          const int* __restrict__ d2, int* __restrict__ count,
                          int* __restrict__ elist) {
    int b = blockIdx.x;
    int m = b / 782;
    int e = (b - m * 782) * 256 + threadIdx.x;
    if (e >= NEDGE) return;
    const int* dst = m == 0 ? d0 : m == 1 ? d1 : d2;
    int d = dst[e];
    int* cnt = count + (size_t)m * NPAR;
    int* el = elist + (size_t)m * NPAR * CAP;
    int slot = atomicAdd(&cnt[d], 1);
    if (slot < CAP) el[(size_t)d * CAP + slot] = e;
}

// ---- pf phase 1: compact matching edges ----
__global__ void k_pf_scan(const int* __restrict__ psrc, const int* __restrict__ pdst,
                          const int* __restrict__ tgtp, int* __restrict__ mlist) {
    int e = blockIdx.x * 256 + threadIdx.x;
    if (e >= NEDGE) return;
    if (pdst[e] == tgtp[0]) {
        int slot = atomicAdd(&mlist[0], 1);
        if (slot < PFCAP) mlist[1 + slot] = psrc[e];
    }
}

// ---- pf phase 2: wave-parallel accumulate over matches (1 block) ----
__global__ void k_pf_acc(const int* __restrict__ mlist, const int* __restrict__ tgtp,
                         const unsigned short* __restrict__ Hpar,
                         const float* __restrict__ as_pf, const float* __restrict__ ad_pf,
                         float* __restrict__ smallb) {
    __shared__ float sacc[4][256];
    __shared__ float sden[4][8];
    int t = threadIdx.x, w = t >> 6, l = t & 63;
    int tgt = tgtp[0];
    int cnt = mlist[0]; if (cnt > PFCAP) cnt = PFCAP;
    int h = l >> 3;
    float adh = ad_pf[tgt * 8 + h];
    float a0 = 0.f, a1 = 0.f, a2 = 0.f, a3 = 0.f, den = 0.f;
    for (int i = w; i < cnt; i += 4) {
        int s = mlist[1 + i];
        float al = as_pf[s * 8 + h] + adh;
        al = al > 0.f ? al : 0.2f * al;
        float ex = __expf(al);
        ushort4 hv = *reinterpret_cast<const ushort4*>(&Hpar[(size_t)s * 256 + l * 4]);
        a0 += ex * b2f(hv.x); a1 += ex * b2f(hv.y); a2 += ex * b2f(hv.z); a3 += ex * b2f(hv.w);
        den += ex;
    }
    sacc[w][l * 4 + 0] = a0; sacc[w][l * 4 + 1] = a1;
    sacc[w][l * 4 + 2] = a2; sacc[w][l * 4 + 3] = a3;
    if ((l & 7) == 0) sden[w][h] = den;
    __syncthreads();
    smallb[t] = sacc[0][t] + sacc[1][t] + sacc[2][t] + sacc[3][t];
    if (t < 8) smallb[256 + t] = sden[0][t] + sden[1][t] + sden[2][t] + sden[3][t];
}

// ---- semantic attention softmax + scalar C ----
__global__ void k_finalize(const float* __restrict__ kacc, const float* __restrict__ q,
                           const float* __restrict__ u, float* __restrict__ smallb) {
    __shared__ float red[256];
    __shared__ float sm[3];
    int t = threadIdx.x;
    float qv = q[t];
    for (int m = 0; m < 3; ++m) {
        red[t] = kacc[m * 256 + t] * qv;
        __syncthreads();
        for (int s = 128; s > 0; s >>= 1) { if (t < s) red[t] += red[t + s]; __syncthreads(); }
        if (t == 0) sm[m] = red[0] / (float)NPAR;
        __syncthreads();
    }
    float den = smallb[256 + (t >> 5)];
    float rt = fmaxf(smallb[t] / (den + 1e-16f), 0.f);
    red[t] = rt * u[t];
    __syncthreads();
    for (int s = 128; s > 0; s >>= 1) { if (t < s) red[t] += red[t + s]; __syncthreads(); }
    if (t == 0) {
        float mx = fmaxf(sm[0], fmaxf(sm[1], sm[2]));
        float e0 = expf(sm[0] - mx), e1 = expf(sm[1] - mx), e2 = expf(sm[2] - mx);
        float sd = e0 + e1 + e2;
        smallb[265] = e0 / sd; smallb[266] = e1 / sd; smallb[267] = e2 / sd;
        smallb[268] = red[0] + smallb[264];
    }
}

// ---- final scores ----
__global__ void k_scores(const float* __restrict__ g, const float* __restrict__ smallb,
                         float* __restrict__ out) {
    int i = blockIdx.x * 256 + threadIdx.x;
    if (i >= NPAR) return;
    out[i] = smallb[268] + smallb[265] * g[i] + smallb[266] * g[NPAR + i] + smallb[267] * g[2 * NPAR + i];
}

extern "C" void kernel_launch(void* const* d_in, const int* in_sizes, int n_in,
                              void* d_out, int out_size, void* d_ws, size_t ws_size,
                              hipStream_t stream) {
    char* base = (char*)d_ws;
    size_t off = 0;
    auto alloc = [&](size_t b) -> void* { void* p = base + off; off += (b + 255) & ~(size_t)255; return p; };

    unsigned short* h_par = (unsigned short*)alloc((size_t)MPAD * 256 * 2);
    unsigned short* h_fig = (unsigned short*)alloc((size_t)NFIG * 256 * 2);
    unsigned short* h_tab = (unsigned short*)alloc((size_t)NTAB * 256 * 2);
    unsigned short* h_cit = (unsigned short*)alloc((size_t)NCIT * 256 * 2);
    unsigned short* WTall = (unsigned short*)alloc((size_t)5 * 65536 * 2);
    unsigned short* WT_par = WTall, *WT_fig = WTall + 65536, *WT_tab = WTall + 2 * 65536,
                  *WT_cit = WTall + 3 * 65536, *kwT = WTall + 4 * 65536;
    float* as_pf = (float*)alloc((size_t)NPAR * 8 * 4);
    float* ad_fp = (float*)alloc((size_t)NPAR * 8 * 4);
    float* ad_tp = (float*)alloc((size_t)NPAR * 8 * 4);
    float* ad_cp = (float*)alloc((size_t)NPAR * 8 * 4);
    float* as_fp = (float*)alloc((size_t)NFIG * 8 * 4);
    float* ad_pf = (float*)alloc((size_t)NFIG * 8 * 4);
    float* as_tp = (float*)alloc((size_t)NTAB * 8 * 4);
    float* as_cp = (float*)alloc((size_t)NCIT * 8 * 4);
    float* gbuf  = (float*)alloc((size_t)3 * NPAR * 4);
    int* count3  = (int*)alloc((size_t)3 * NPAR * 4);
    int* elist3  = (int*)alloc((size_t)3 * NPAR * CAP * 4);
    float* kacc  = (float*)alloc(3 * 256 * 4);       // contiguous scalar block begins
    float* smallb = (float*)alloc(512 * 4);
    int* mlist   = (int*)alloc((1 + PFCAP) * 4);
    float* uvec  = (float*)alloc(256 * 4);
    float* vvec  = (float*)alloc(256 * 4);

    hipMemsetAsync(kacc, 0, 5632, stream);
    hipMemsetAsync(count3, 0, (size_t)3 * NPAR * 4, stream);

    k_transpose5<<<5 * 256, 256, 0, stream>>>((const float*)d_in[4], (const float*)d_in[6],
                                              (const float*)d_in[8], (const float*)d_in[10],
                                              (const float*)d_in[24], WTall);

    k_precompute<<<1, 256, 0, stream>>>((const float*)d_in[29], (const float*)d_in[30],
                                        (const float*)d_in[27], (const float*)d_in[28],
                                        (const float*)d_in[35], (const float*)d_in[36],
                                        uvec, vvec, smallb);

    k_bucket3<<<3 * 782, 256, 0, stream>>>((const int*)d_in[40], (const int*)d_in[44],
                                           (const int*)d_in[48], count3, elist3);
    k_pf_scan<<<782, 256, 0, stream>>>((const int*)d_in[37], (const int*)d_in[38],
                                       (const int*)d_in[49], mlist);

    ProjPack pp;
    pp.X[0] = (const float*)d_in[0]; pp.X[1] = (const float*)d_in[1];
    pp.X[2] = (const float*)d_in[2]; pp.X[3] = (const float*)d_in[3];
    pp.WT[0] = WT_par; pp.WT[1] = WT_fig; pp.WT[2] = WT_tab; pp.WT[3] = WT_cit;
    pp.bias[0] = (const float*)d_in[5]; pp.bias[1] = (const float*)d_in[7];
    pp.bias[2] = (const float*)d_in[9]; pp.bias[3] = (const float*)d_in[11];
    pp.H[0] = h_par; pp.H[1] = h_fig; pp.H[2] = h_tab; pp.H[3] = h_cit;
    pp.nrows[0] = NPAR; pp.nrows[1] = NFIG; pp.nrows[2] = NTAB; pp.nrows[3] = NCIT;
    pp.bbase[0] = 0; pp.bbase[1] = 782; pp.bbase[2] = 939; pp.bbase[3] = 1096;
    pp.nv[0] = 4; pp.nv[1] = 2; pp.nv[2] = 1; pp.nv[3] = 1;
    for (int i = 0; i < 16; ++i) { pp.av[i] = nullptr; pp.ov[i] = nullptr; }
    pp.av[0] = (const float*)d_in[12]; pp.ov[0] = as_pf;   // par
    pp.av[1] = (const float*)d_in[15]; pp.ov[1] = ad_fp;
    pp.av[2] = (const float*)d_in[19]; pp.ov[2] = ad_tp;
    pp.av[3] = (const float*)d_in[23]; pp.ov[3] = ad_cp;
    pp.av[4] = (const float*)d_in[14]; pp.ov[4] = as_fp;   // fig
    pp.av[5] = (const float*)d_in[13]; pp.ov[5] = ad_pf;
    pp.av[8] = (const float*)d_in[18]; pp.ov[8] = as_tp;   // tab
    pp.av[12] = (const float*)d_in[22]; pp.ov[12] = as_cp; // cit
    k_gemm_proj<<<1487, 512, 0, stream>>>(pp);

    k_pf_acc<<<1, 256, 0, stream>>>(mlist, (const int*)d_in[49], h_par, as_pf, ad_pf, smallb);

    const int* srcs[3] = { (const int*)d_in[39], (const int*)d_in[43], (const int*)d_in[47] };
    const unsigned short* hsrcs[3] = { h_fig, h_tab, h_cit };
    const float* ass[3] = { as_fp, as_tp, as_cp };
    const float* ads[3] = { ad_fp, ad_tp, ad_cp };
    for (int m = 0; m < 3; ++m) {
        k_gather_kmean<<<782, 512, 0, stream>>>(srcs[m], count3 + (size_t)m * NPAR,
                                                elist3 + (size_t)m * NPAR * CAP, hsrcs[m],
                                                ass[m], ads[m], kwT, (const float*)d_in[25],
                                                vvec, kacc + m * 256, gbuf + (size_t)m * NPAR);
    }

    k_finalize<<<1, 256, 0, stream>>>(kacc, (const float*)d_in[26], uvec, smallb);
    k_scores<<<391, 256, 0, stream>>>(gbuf, smallb, (float*)d_out);
}

// Round 6
// 502.856 us; speedup vs baseline: 1.2680x; 1.2680x over previous
//
#include <hip/hip_runtime.h>
#include <hip/hip_bf16.h>
#include <math.h>

typedef float f32x4 __attribute__((ext_vector_type(4)));
typedef short bf16x8 __attribute__((ext_vector_type(8)));

#define NPAR 100000
#define NFIG 20000
#define NTAB 20000
#define NCIT 50000
#define NEDGE 200000
#define CAP 32
#define MPAD 100096
#define PFCAP 79

__device__ __forceinline__ unsigned short f2b(float f) {
    union { float f; unsigned u; } x; x.f = f;
    unsigned r = x.u + 0x7FFFu + ((x.u >> 16) & 1u);
    return (unsigned short)(r >> 16);
}
__device__ __forceinline__ float b2f(unsigned short b) {
    union { unsigned u; float f; } x; x.u = ((unsigned)b) << 16; return x.f;
}
__device__ __forceinline__ float fast_tanh(float x) {
    float e = __expf(2.f * x);
    return 1.f - 2.f * __builtin_amdgcn_rcpf(e + 1.f);
}
__device__ __forceinline__ void async_copy16(const unsigned short* g, unsigned short* l) {
    __builtin_amdgcn_global_load_lds(
        (const __attribute__((address_space(1))) unsigned int*)g,
        (__attribute__((address_space(3))) unsigned int*)l, 16, 0, 0);
}

// ---- 5 weight transposes in one launch: W [256,256] f32 (k,n) -> WT bf16 [n][k] ----
__global__ void k_transpose5(const float* __restrict__ W0, const float* __restrict__ W1,
                             const float* __restrict__ W2, const float* __restrict__ W3,
                             const float* __restrict__ W4, unsigned short* __restrict__ WT) {
    int b = blockIdx.x, which = b >> 8, k = b & 255, n = threadIdx.x;
    const float* W = which == 0 ? W0 : which == 1 ? W1 : which == 2 ? W2 : which == 3 ? W3 : W4;
    WT[(size_t)which * 65536 + n * 256 + k] = f2b(W[k * 256 + n]);
}

// ---- u = Wh_fig @ cls_w1, v = Wh_par @ cls_w2, Cpart ----
__global__ void k_precompute(const float* __restrict__ WhF, const float* __restrict__ bhF,
                             const float* __restrict__ WhP, const float* __restrict__ bhP,
                             const float* __restrict__ clsw, const float* __restrict__ clsb,
                             float* __restrict__ u, float* __restrict__ v, float* __restrict__ smallb) {
    int t = threadIdx.x;
    float su = 0.f, sv = 0.f;
    for (int j = 0; j < 128; ++j) {
        su += WhF[t * 128 + j] * clsw[j];
        sv += WhP[t * 128 + j] * clsw[128 + j];
    }
    u[t] = su; v[t] = sv;
    if (t == 0) {
        float c = clsb[0];
        for (int j = 0; j < 128; ++j) c += bhF[j] * clsw[j] + bhP[j] * clsw[128 + j];
        smallb[264] = c;
    }
}

// ---- merged projection GEMM (R4 main loop) + in-register fused att epilogue ----
struct ProjPack {
    const float* X[4];
    const unsigned short* WT[4];
    const float* bias[4];
    unsigned short* H[4];
    const float* av[16];   // [ty*4+v]
    float* ov[16];
    int nrows[4];
    int bbase[4];
    int nv[4];
};
__global__ __launch_bounds__(512, 4) void k_gemm_proj(ProjPack p) {
    __shared__ __align__(16) unsigned short As[2][128 * 32];   // 16 KB
    __shared__ __align__(16) unsigned short Bs[2][256 * 32];   // 32 KB
    __shared__ float satt[4][128][8];                          // 16 KB
    int bid = blockIdx.x;
    int ty = (bid >= p.bbase[1]) + (bid >= p.bbase[2]) + (bid >= p.bbase[3]);
    int m0 = (bid - p.bbase[ty]) * 128;
    const float* Xf = p.X[ty];
    const unsigned short* B = p.WT[ty];
    unsigned short* Hout = p.H[ty];
    int Nrows = p.nrows[ty];
    int nv = p.nv[ty];

    int t = threadIdx.x, l = t & 63, w = t >> 6;
    int wm = (w >> 2) * 64, wn = (w & 3) * 64;
    int lr = l & 15, hi = l >> 4;
    int arow = t >> 2, acol = (t & 3) * 8;
    bool aok = (m0 + arow) < Nrows;
    const float* Arow = Xf + (size_t)(m0 + arow) * 256 + acol;
    f32x4 acc[4][4] = {};
    float4 a4[2];

    auto loadA = [&](int k0) {
        if (aok) {
            const float4* ptr = reinterpret_cast<const float4*>(Arow + k0);
            a4[0] = ptr[0]; a4[1] = ptr[1];
        } else {
            a4[0] = a4[1] = make_float4(0.f, 0.f, 0.f, 0.f);
        }
    };
    auto writeA = [&](int buf) {
        __align__(16) unsigned short tmp[8];
        tmp[0] = f2b(a4[0].x); tmp[1] = f2b(a4[0].y); tmp[2] = f2b(a4[0].z); tmp[3] = f2b(a4[0].w);
        tmp[4] = f2b(a4[1].x); tmp[5] = f2b(a4[1].y); tmp[6] = f2b(a4[1].z); tmp[7] = f2b(a4[1].w);
        *reinterpret_cast<uint4*>(&As[buf][arow * 32 + acol]) = *reinterpret_cast<const uint4*>(tmp);
    };
    auto stageB = [&](int buf, int k0) {
#pragma unroll
        for (int i = 0; i < 2; ++i) {
            int rowb = w * 32 + i * 16;
            async_copy16(B + (size_t)(rowb + (l >> 2)) * 256 + k0 + (l & 3) * 8,
                         &Bs[buf][rowb * 32]);
        }
    };

    loadA(0); stageB(0, 0); writeA(0);
    __syncthreads();
    int cur = 0;
    for (int ks = 0; ks < 8; ++ks) {
        if (ks < 7) { loadA((ks + 1) * 32); stageB(cur ^ 1, (ks + 1) * 32); }
        bf16x8 af[4], bfr[4];
#pragma unroll
        for (int mm = 0; mm < 4; ++mm)
            af[mm] = *reinterpret_cast<const bf16x8*>(&As[cur][(wm + mm * 16 + lr) * 32 + hi * 8]);
#pragma unroll
        for (int nn = 0; nn < 4; ++nn)
            bfr[nn] = *reinterpret_cast<const bf16x8*>(&Bs[cur][(wn + nn * 16 + lr) * 32 + hi * 8]);
#pragma unroll
        for (int mm = 0; mm < 4; ++mm)
#pragma unroll
            for (int nn = 0; nn < 4; ++nn)
                acc[mm][nn] = __builtin_amdgcn_mfma_f32_16x16x32_bf16(af[mm], bfr[nn], acc[mm][nn], 0, 0, 0);
        if (ks < 7) writeA(cur ^ 1);
        __syncthreads();
        cur ^= 1;
    }

    // ---- epilogue (post-loop, no state carried across K-loop) ----
    float bv[4], avr[4][4];
#pragma unroll
    for (int nn = 0; nn < 4; ++nn) bv[nn] = p.bias[ty][wn + nn * 16 + lr];
#pragma unroll
    for (int v = 0; v < 4; ++v)
        if (v < nv) {
            const float* A = p.av[ty * 4 + v];
#pragma unroll
            for (int nn = 0; nn < 4; ++nn) avr[v][nn] = A[wn + nn * 16 + lr];
        }
    int h0 = (w & 3) * 2;
#pragma unroll
    for (int mm = 0; mm < 4; ++mm)
#pragma unroll
        for (int r = 0; r < 4; ++r) {
            int lrow = wm + mm * 16 + hi * 4 + r;
            int row = m0 + lrow;
            float s[4][2] = {};
#pragma unroll
            for (int nn = 0; nn < 4; ++nn) {
                float cb = acc[mm][nn][r] + bv[nn];
                if (row < Nrows) Hout[(size_t)row * 256 + wn + nn * 16 + lr] = f2b(cb);
#pragma unroll
                for (int v = 0; v < 4; ++v)
                    if (v < nv) s[v][nn >> 1] += cb * avr[v][nn];
            }
#pragma unroll
            for (int v = 0; v < 4; ++v)
                if (v < nv) {
                    float s0 = s[v][0], s1 = s[v][1];
                    s0 += __shfl_xor(s0, 1); s0 += __shfl_xor(s0, 2);
                    s0 += __shfl_xor(s0, 4); s0 += __shfl_xor(s0, 8);
                    s1 += __shfl_xor(s1, 1); s1 += __shfl_xor(s1, 2);
                    s1 += __shfl_xor(s1, 4); s1 += __shfl_xor(s1, 8);
                    if (lr == 0) { satt[v][lrow][h0] = s0; satt[v][lrow][h0 + 1] = s1; }
                }
        }
    __syncthreads();
    for (int i = t; i < nv * 1024; i += 512) {
        int v = i >> 10, rem = i & 1023, lrow = rem >> 3, hd = rem & 7;
        int g = m0 + lrow;
        if (g < Nrows) p.ov[ty * 4 + v][(size_t)g * 8 + hd] = satt[v][lrow][hd];
    }
}

// ---- fused gather + kmean: 64-dst tile (64 KB LDS -> 2 blocks/CU) ----
__global__ __launch_bounds__(512, 4) void k_gather_kmean(
    const int* __restrict__ src, const int* __restrict__ count,
    const int* __restrict__ elist, const unsigned short* __restrict__ Hsrc,
    const float* __restrict__ as_, const float* __restrict__ ad_,
    const unsigned short* __restrict__ Bw, const float* __restrict__ kb,
    const float* __restrict__ v, float* __restrict__ ksum,
    float* __restrict__ gout) {
    __shared__ __align__(16) unsigned short Ar[64 * 256];      // 32 KB, swizzled
    __shared__ __align__(16) unsigned short Bs[2][256 * 32];   // 32 KB
    int t = threadIdx.x, l = t & 63, w = t >> 6;
    int m0 = blockIdx.x * 64;
    int lg = l & 15, gb = l & 48;

    auto stageB = [&](int buf, int k0) {
#pragma unroll
        for (int i = 0; i < 2; ++i) {
            int rowb = w * 32 + i * 16;
            async_copy16(Bw + (size_t)(rowb + (l >> 2)) * 256 + k0 + (l & 3) * 8,
                         &Bs[buf][rowb * 32]);
        }
    };
    stageB(0, 0);   // B loads fly during gather

    float vr[16];
#pragma unroll
    for (int k = 0; k < 16; ++k) vr[k] = v[lg * 16 + k];

    // gather: 2 rounds, one dst per 16-lane group
    for (int j = 0; j < 2; ++j) {
        int ld = w * 8 + j * 4 + (l >> 4);   // 0..63
        int d = m0 + ld;
        bool valid = d < NPAR;
        int cnt = 0;
        if (valid) { cnt = count[d]; if (cnt > CAP) cnt = CAP; }
        int s1 = 0, s2 = 0;
        if (lg < cnt) s1 = src[elist[(size_t)d * CAP + lg]];
        if (lg + 16 < cnt) s2 = src[elist[(size_t)d * CAP + lg + 16]];
        float adh = valid ? ad_[d * 8 + (lg >> 1)] : 0.f;
        float ar[16];
#pragma unroll
        for (int k = 0; k < 16; ++k) ar[k] = 0.f;
        float den = 0.f;
        for (int i = 0; i < cnt; ++i) {
            int s = (i < 16) ? __shfl(s1, gb + i) : __shfl(s2, gb + i - 16);
            float al = as_[s * 8 + (lg >> 1)] + adh;
            al = al > 0.f ? al : 0.2f * al;
            float ex = __expf(al); den += ex;
            const uint4* hp = reinterpret_cast<const uint4*>(Hsrc + (size_t)s * 256 + lg * 16);
            uint4 hv0 = hp[0], hv1 = hp[1];
            unsigned wds[8] = { hv0.x, hv0.y, hv0.z, hv0.w, hv1.x, hv1.y, hv1.z, hv1.w };
#pragma unroll
            for (int k = 0; k < 8; ++k) {
                ar[k * 2]     += ex * b2f((unsigned short)(wds[k] & 0xffffu));
                ar[k * 2 + 1] += ex * b2f((unsigned short)(wds[k] >> 16));
            }
        }
        float inv = 1.f / (den + 1e-16f);
        float gs = 0.f;
        __align__(16) unsigned short ob[16];
#pragma unroll
        for (int k = 0; k < 16; ++k) {
            float r = fmaxf(ar[k] * inv, 0.f);
            gs += r * vr[k];
            ob[k] = f2b(r);
        }
        int u0 = (lg * 2) ^ (ld & 7), u1 = (lg * 2 + 1) ^ (ld & 7);
        *reinterpret_cast<uint4*>(&Ar[ld * 256 + u0 * 8]) = *reinterpret_cast<const uint4*>(ob);
        *reinterpret_cast<uint4*>(&Ar[ld * 256 + u1 * 8]) = *reinterpret_cast<const uint4*>(ob + 8);
        gs += __shfl_xor(gs, 1); gs += __shfl_xor(gs, 2); gs += __shfl_xor(gs, 4); gs += __shfl_xor(gs, 8);
        if (lg == 0 && valid) gout[d] = gs;
    }
    __syncthreads();

    // GEMM: A resident in Ar (swizzled), B double-buffered linear
    int wm = (w >> 2) * 32, wn = (w & 3) * 64, lr = l & 15, hi = l >> 4;
    f32x4 acc[2][4] = {};
    int cur = 0;
    for (int ks = 0; ks < 8; ++ks) {
        if (ks < 7) stageB(cur ^ 1, (ks + 1) * 32);
        bf16x8 af[2], bfr[4];
#pragma unroll
        for (int mm = 0; mm < 2; ++mm) {
            int rr = wm + mm * 16 + lr;
            af[mm] = *reinterpret_cast<const bf16x8*>(&Ar[rr * 256 + (((ks * 4 + hi) ^ (rr & 7)) * 8)]);
        }
#pragma unroll
        for (int nn = 0; nn < 4; ++nn)
            bfr[nn] = *reinterpret_cast<const bf16x8*>(&Bs[cur][(wn + nn * 16 + lr) * 32 + hi * 8]);
#pragma unroll
        for (int mm = 0; mm < 2; ++mm)
#pragma unroll
            for (int nn = 0; nn < 4; ++nn)
                acc[mm][nn] = __builtin_amdgcn_mfma_f32_16x16x32_bf16(af[mm], bfr[nn], acc[mm][nn], 0, 0, 0);
        __syncthreads();
        cur ^= 1;
    }
#pragma unroll
    for (int nn = 0; nn < 4; ++nn) {
        int col = wn + nn * 16 + lr;
        float kbv = kb[col];
        float cs = 0.f;
#pragma unroll
        for (int mm = 0; mm < 2; ++mm)
#pragma unroll
            for (int r = 0; r < 4; ++r) {
                int row = m0 + wm + mm * 16 + hi * 4 + r;
                if (row < NPAR) cs += fast_tanh(acc[mm][nn][r] + kbv);
            }
        cs += __shfl_xor(cs, 16);
        cs += __shfl_xor(cs, 32);
        if (hi == 0) atomicAdd(&ksum[col], cs);
    }
}

// ---- bucket all 3 metapaths in one launch ----
__global__ void k_bucket3(const int* __restrict__ d0, const int* __restrict__ d1,
                          const int* __restrict__ d2, int* __restrict__ count,
                          int* __restrict__ elist) {
    int b = blockIdx.x;
    int m = b / 782;
    int e = (b - m * 782) * 256 + threadIdx.x;
    if (e >= NEDGE) return;
    const int* dst = m == 0 ? d0 : m == 1 ? d1 : d2;
    int d = dst[e];
    int* cnt = count + (size_t)m * NPAR;
    int* el = elist + (size_t)m * NPAR * CAP;
    int slot = atomicAdd(&cnt[d], 1);
    if (slot < CAP) el[(size_t)d * CAP + slot] = e;
}

// ---- pf phase 1: compact matching edges ----
__global__ void k_pf_scan(const int* __restrict__ psrc, const int* __restrict__ pdst,
                          const int* __restrict__ tgtp, int* __restrict__ mlist) {
    int e = blockIdx.x * 256 + threadIdx.x;
    if (e >= NEDGE) return;
    if (pdst[e] == tgtp[0]) {
        int slot = atomicAdd(&mlist[0], 1);
        if (slot < PFCAP) mlist[1 + slot] = psrc[e];
    }
}

// ---- pf phase 2: wave-parallel accumulate over matches (1 block) ----
__global__ void k_pf_acc(const int* __restrict__ mlist, const int* __restrict__ tgtp,
                         const unsigned short* __restrict__ Hpar,
                         const float* __restrict__ as_pf, const float* __restrict__ ad_pf,
                         float* __restrict__ smallb) {
    __shared__ float sacc[4][256];
    __shared__ float sden[4][8];
    int t = threadIdx.x, w = t >> 6, l = t & 63;
    int tgt = tgtp[0];
    int cnt = mlist[0]; if (cnt > PFCAP) cnt = PFCAP;
    int h = l >> 3;
    float adh = ad_pf[tgt * 8 + h];
    float a0 = 0.f, a1 = 0.f, a2 = 0.f, a3 = 0.f, den = 0.f;
    for (int i = w; i < cnt; i += 4) {
        int s = mlist[1 + i];
        float al = as_pf[s * 8 + h] + adh;
        al = al > 0.f ? al : 0.2f * al;
        float ex = __expf(al);
        ushort4 hv = *reinterpret_cast<const ushort4*>(&Hpar[(size_t)s * 256 + l * 4]);
        a0 += ex * b2f(hv.x); a1 += ex * b2f(hv.y); a2 += ex * b2f(hv.z); a3 += ex * b2f(hv.w);
        den += ex;
    }
    sacc[w][l * 4 + 0] = a0; sacc[w][l * 4 + 1] = a1;
    sacc[w][l * 4 + 2] = a2; sacc[w][l * 4 + 3] = a3;
    if ((l & 7) == 0) sden[w][h] = den;
    __syncthreads();
    smallb[t] = sacc[0][t] + sacc[1][t] + sacc[2][t] + sacc[3][t];
    if (t < 8) smallb[256 + t] = sden[0][t] + sden[1][t] + sden[2][t] + sden[3][t];
}

// ---- semantic attention softmax + scalar C ----
__global__ void k_finalize(const float* __restrict__ kacc, const float* __restrict__ q,
                           const float* __restrict__ u, float* __restrict__ smallb) {
    __shared__ float red[256];
    __shared__ float sm[3];
    int t = threadIdx.x;
    float qv = q[t];
    for (int m = 0; m < 3; ++m) {
        red[t] = kacc[m * 256 + t] * qv;
        __syncthreads();
        for (int s = 128; s > 0; s >>= 1) { if (t < s) red[t] += red[t + s]; __syncthreads(); }
        if (t == 0) sm[m] = red[0] / (float)NPAR;
        __syncthreads();
    }
    float den = smallb[256 + (t >> 5)];
    float rt = fmaxf(smallb[t] / (den + 1e-16f), 0.f);
    red[t] = rt * u[t];
    __syncthreads();
    for (int s = 128; s > 0; s >>= 1) { if (t < s) red[t] += red[t + s]; __syncthreads(); }
    if (t == 0) {
        float mx = fmaxf(sm[0], fmaxf(sm[1], sm[2]));
        float e0 = expf(sm[0] - mx), e1 = expf(sm[1] - mx), e2 = expf(sm[2] - mx);
        float sd = e0 + e1 + e2;
        smallb[265] = e0 / sd; smallb[266] = e1 / sd; smallb[267] = e2 / sd;
        smallb[268] = red[0] + smallb[264];
    }
}

// ---- final scores ----
__global__ void k_scores(const float* __restrict__ g, const float* __restrict__ smallb,
                         float* __restrict__ out) {
    int i = blockIdx.x * 256 + threadIdx.x;
    if (i >= NPAR) return;
    out[i] = smallb[268] + smallb[265] * g[i] + smallb[266] * g[NPAR + i] + smallb[267] * g[2 * NPAR + i];
}

extern "C" void kernel_launch(void* const* d_in, const int* in_sizes, int n_in,
                              void* d_out, int out_size, void* d_ws, size_t ws_size,
                              hipStream_t stream) {
    char* base = (char*)d_ws;
    size_t off = 0;
    auto alloc = [&](size_t b) -> void* { void* p = base + off; off += (b + 255) & ~(size_t)255; return p; };

    unsigned short* h_par = (unsigned short*)alloc((size_t)MPAD * 256 * 2);
    unsigned short* h_fig = (unsigned short*)alloc((size_t)NFIG * 256 * 2);
    unsigned short* h_tab = (unsigned short*)alloc((size_t)NTAB * 256 * 2);
    unsigned short* h_cit = (unsigned short*)alloc((size_t)NCIT * 256 * 2);
    unsigned short* WTall = (unsigned short*)alloc((size_t)5 * 65536 * 2);
    unsigned short* WT_par = WTall, *WT_fig = WTall + 65536, *WT_tab = WTall + 2 * 65536,
                  *WT_cit = WTall + 3 * 65536, *kwT = WTall + 4 * 65536;
    float* as_pf = (float*)alloc((size_t)NPAR * 8 * 4);
    float* ad_fp = (float*)alloc((size_t)NPAR * 8 * 4);
    float* ad_tp = (float*)alloc((size_t)NPAR * 8 * 4);
    float* ad_cp = (float*)alloc((size_t)NPAR * 8 * 4);
    float* as_fp = (float*)alloc((size_t)NFIG * 8 * 4);
    float* ad_pf = (float*)alloc((size_t)NFIG * 8 * 4);
    float* as_tp = (float*)alloc((size_t)NTAB * 8 * 4);
    float* as_cp = (float*)alloc((size_t)NCIT * 8 * 4);
    float* gbuf  = (float*)alloc((size_t)3 * NPAR * 4);
    int* count3  = (int*)alloc((size_t)3 * NPAR * 4);
    int* elist3  = (int*)alloc((size_t)3 * NPAR * CAP * 4);
    float* kacc  = (float*)alloc(3 * 256 * 4);
    float* smallb = (float*)alloc(512 * 4);
    int* mlist   = (int*)alloc((1 + PFCAP) * 4);
    float* uvec  = (float*)alloc(256 * 4);
    float* vvec  = (float*)alloc(256 * 4);

    hipMemsetAsync(kacc, 0, 5632, stream);
    hipMemsetAsync(count3, 0, (size_t)3 * NPAR * 4, stream);

    k_transpose5<<<5 * 256, 256, 0, stream>>>((const float*)d_in[4], (const float*)d_in[6],
                                              (const float*)d_in[8], (const float*)d_in[10],
                                              (const float*)d_in[24], WTall);

    k_precompute<<<1, 256, 0, stream>>>((const float*)d_in[29], (const float*)d_in[30],
                                        (const float*)d_in[27], (const float*)d_in[28],
                                        (const float*)d_in[35], (const float*)d_in[36],
                                        uvec, vvec, smallb);

    k_bucket3<<<3 * 782, 256, 0, stream>>>((const int*)d_in[40], (const int*)d_in[44],
                                           (const int*)d_in[48], count3, elist3);
    k_pf_scan<<<782, 256, 0, stream>>>((const int*)d_in[37], (const int*)d_in[38],
                                       (const int*)d_in[49], mlist);

    ProjPack pp;
    pp.X[0] = (const float*)d_in[0]; pp.X[1] = (const float*)d_in[1];
    pp.X[2] = (const float*)d_in[2]; pp.X[3] = (const float*)d_in[3];
    pp.WT[0] = WT_par; pp.WT[1] = WT_fig; pp.WT[2] = WT_tab; pp.WT[3] = WT_cit;
    pp.bias[0] = (const float*)d_in[5]; pp.bias[1] = (const float*)d_in[7];
    pp.bias[2] = (const float*)d_in[9]; pp.bias[3] = (const float*)d_in[11];
    pp.H[0] = h_par; pp.H[1] = h_fig; pp.H[2] = h_tab; pp.H[3] = h_cit;
    pp.nrows[0] = NPAR; pp.nrows[1] = NFIG; pp.nrows[2] = NTAB; pp.nrows[3] = NCIT;
    pp.bbase[0] = 0; pp.bbase[1] = 782; pp.bbase[2] = 939; pp.bbase[3] = 1096;
    pp.nv[0] = 4; pp.nv[1] = 2; pp.nv[2] = 1; pp.nv[3] = 1;
    for (int i = 0; i < 16; ++i) { pp.av[i] = nullptr; pp.ov[i] = nullptr; }
    pp.av[0] = (const float*)d_in[12]; pp.ov[0] = as_pf;   // par
    pp.av[1] = (const float*)d_in[15]; pp.ov[1] = ad_fp;
    pp.av[2] = (const float*)d_in[19]; pp.ov[2] = ad_tp;
    pp.av[3] = (const float*)d_in[23]; pp.ov[3] = ad_cp;
    pp.av[4] = (const float*)d_in[14]; pp.ov[4] = as_fp;   // fig
    pp.av[5] = (const float*)d_in[13]; pp.ov[5] = ad_pf;
    pp.av[8] = (const float*)d_in[18]; pp.ov[8] = as_tp;   // tab
    pp.av[12] = (const float*)d_in[22]; pp.ov[12] = as_cp; // cit
    k_gemm_proj<<<1487, 512, 0, stream>>>(pp);

    k_pf_acc<<<1, 256, 0, stream>>>(mlist, (const int*)d_in[49], h_par, as_pf, ad_pf, smallb);

    const int* srcs[3] = { (const int*)d_in[39], (const int*)d_in[43], (const int*)d_in[47] };
    const unsigned short* hsrcs[3] = { h_fig, h_tab, h_cit };
    const float* ass[3] = { as_fp, as_tp, as_cp };
    const float* ads[3] = { ad_fp, ad_tp, ad_cp };
    for (int m = 0; m < 3; ++m) {
        k_gather_kmean<<<1563, 512, 0, stream>>>(srcs[m], count3 + (size_t)m * NPAR,
                                                 elist3 + (size_t)m * NPAR * CAP, hsrcs[m],
                                                 ass[m], ads[m], kwT, (const float*)d_in[25],
                                                 vvec, kacc + m * 256, gbuf + (size_t)m * NPAR);
    }

    k_finalize<<<1, 256, 0, stream>>>(kacc, (const float*)d_in[26], uvec, smallb);
    k_scores<<<391, 256, 0, stream>>>(gbuf, smallb, (float*)d_out);
}

// Round 7
// 497.212 us; speedup vs baseline: 1.2824x; 1.0114x over previous
//
#include <hip/hip_runtime.h>
#include <hip/hip_bf16.h>
#include <math.h>

typedef float f32x4 __attribute__((ext_vector_type(4)));
typedef short bf16x8 __attribute__((ext_vector_type(8)));

#define NPAR 100000
#define NFIG 20000
#define NTAB 20000
#define NCIT 50000
#define NEDGE 200000
#define CAP 32
#define MPAD 100096
#define PFCAP 79

__device__ __forceinline__ unsigned short f2b(float f) {
    union { float f; unsigned u; } x; x.f = f;
    unsigned r = x.u + 0x7FFFu + ((x.u >> 16) & 1u);
    return (unsigned short)(r >> 16);
}
__device__ __forceinline__ float b2f(unsigned short b) {
    union { unsigned u; float f; } x; x.u = ((unsigned)b) << 16; return x.f;
}
__device__ __forceinline__ float fast_tanh(float x) {
    float e = __expf(2.f * x);
    return 1.f - 2.f * __builtin_amdgcn_rcpf(e + 1.f);
}
__device__ __forceinline__ void async_copy16(const unsigned short* g, unsigned short* l) {
    __builtin_amdgcn_global_load_lds(
        (const __attribute__((address_space(1))) unsigned int*)g,
        (__attribute__((address_space(3))) unsigned int*)l, 16, 0, 0);
}

// ---- 5 weight transposes in one launch ----
__global__ void k_transpose5(const float* __restrict__ W0, const float* __restrict__ W1,
                             const float* __restrict__ W2, const float* __restrict__ W3,
                             const float* __restrict__ W4, unsigned short* __restrict__ WT) {
    int b = blockIdx.x, which = b >> 8, k = b & 255, n = threadIdx.x;
    const float* W = which == 0 ? W0 : which == 1 ? W1 : which == 2 ? W2 : which == 3 ? W3 : W4;
    WT[(size_t)which * 65536 + n * 256 + k] = f2b(W[k * 256 + n]);
}

// ---- u = Wh_fig @ cls_w1, v = Wh_par @ cls_w2, Cpart ----
__global__ void k_precompute(const float* __restrict__ WhF, const float* __restrict__ bhF,
                             const float* __restrict__ WhP, const float* __restrict__ bhP,
                             const float* __restrict__ clsw, const float* __restrict__ clsb,
                             float* __restrict__ u, float* __restrict__ v, float* __restrict__ smallb) {
    int t = threadIdx.x;
    float su = 0.f, sv = 0.f;
    for (int j = 0; j < 128; ++j) {
        su += WhF[t * 128 + j] * clsw[j];
        sv += WhP[t * 128 + j] * clsw[128 + j];
    }
    u[t] = su; v[t] = sv;
    if (t == 0) {
        float c = clsb[0];
        for (int j = 0; j < 128; ++j) c += bhF[j] * clsw[j] + bhP[j] * clsw[128 + j];
        smallb[264] = c;
    }
}

// ---- merged projection GEMM: operand-swapped MFMA, counted-vmcnt pipeline, fused att ----
struct ProjPack {
    const float* X[4];
    const unsigned short* WT[4];
    const float* bias[4];
    unsigned short* H[4];
    const float* av[16];
    float* ov[16];
    int nrows[4];
    int bbase[4];
    int nv[4];
};

#define LOADA(k0, A0, A1) do { \
    const float4* _p = reinterpret_cast<const float4*>(Arow + (k0)); \
    A0 = _p[0]; A1 = _p[1]; } while (0)
#define WRITEA(buf, A0, A1) do { \
    __align__(16) unsigned short _t[8]; \
    _t[0] = f2b(A0.x); _t[1] = f2b(A0.y); _t[2] = f2b(A0.z); _t[3] = f2b(A0.w); \
    _t[4] = f2b(A1.x); _t[5] = f2b(A1.y); _t[6] = f2b(A1.z); _t[7] = f2b(A1.w); \
    *reinterpret_cast<uint4*>(&As[buf][arow * 32 + acol]) = *reinterpret_cast<const uint4*>(_t); } while (0)

__global__ __launch_bounds__(512, 4) void k_gemm_proj(ProjPack p) {
    __shared__ __align__(16) unsigned short As[2][128 * 32];   // 16 KB
    __shared__ __align__(16) unsigned short Bs[2][256 * 32];   // 32 KB
    __shared__ float satt[4][128][8];                          // 16 KB
    int bid = blockIdx.x;
    int ty = (bid >= p.bbase[1]) + (bid >= p.bbase[2]) + (bid >= p.bbase[3]);
    int m0 = (bid - p.bbase[ty]) * 128;
    const float* Xf = p.X[ty];
    const unsigned short* B = p.WT[ty];
    unsigned short* Hout = p.H[ty];
    int Nrows = p.nrows[ty];
    int nv = p.nv[ty];

    int t = threadIdx.x, l = t & 63, w = t >> 6;
    int wm = (w >> 2) * 64, wn = (w & 3) * 64;
    int lr = l & 15, hi = l >> 4;
    int arow = t >> 2, acol = (t & 3) * 8;
    // wave-uniform A load: clamp row (outputs for clamped rows are guarded at store)
    int arow_c = m0 + arow; if (arow_c > Nrows - 1) arow_c = Nrows - 1;
    const float* Arow = Xf + (size_t)arow_c * 256 + acol;
    f32x4 acc[4][4] = {};
    float4 aP0, aP1, aQ0, aQ1;

    auto stageB = [&](int buf, int k0) {
#pragma unroll
        for (int i = 0; i < 2; ++i) {
            int rowb = w * 32 + i * 16;
            async_copy16(B + (size_t)(rowb + (l >> 2)) * 256 + k0 + (l & 3) * 8,
                         &Bs[buf][rowb * 32]);
        }
    };

    LOADA(0, aP0, aP1);
    stageB(0, 0);
    WRITEA(0, aP0, aP1);
    LOADA(32, aQ0, aQ1);
    asm volatile("s_waitcnt vmcnt(2) lgkmcnt(0)" ::: "memory");
    __builtin_amdgcn_s_barrier();

#pragma unroll
    for (int ks = 0; ks < 8; ++ks) {
        int cur = ks & 1;
        if (ks < 7) stageB(cur ^ 1, (ks + 1) * 32);
        if (ks < 6) {
            if ((ks & 1) == 0) LOADA((ks + 2) * 32, aP0, aP1);
            else               LOADA((ks + 2) * 32, aQ0, aQ1);
        }
        bf16x8 af[4], bfr[4];
#pragma unroll
        for (int mm = 0; mm < 4; ++mm)
            af[mm] = *reinterpret_cast<const bf16x8*>(&As[cur][(wm + mm * 16 + lr) * 32 + hi * 8]);
#pragma unroll
        for (int nn = 0; nn < 4; ++nn)
            bfr[nn] = *reinterpret_cast<const bf16x8*>(&Bs[cur][(wn + nn * 16 + lr) * 32 + hi * 8]);
#pragma unroll
        for (int mm = 0; mm < 4; ++mm)
#pragma unroll
            for (int nn = 0; nn < 4; ++nn)   // swapped operands: D[m=lane&15][n=(lane>>4)*4+reg]
                acc[mm][nn] = __builtin_amdgcn_mfma_f32_16x16x32_bf16(bfr[nn], af[mm], acc[mm][nn], 0, 0, 0);
        if (ks < 7) {
            if ((ks & 1) == 0) WRITEA(cur ^ 1, aQ0, aQ1);
            else               WRITEA(cur ^ 1, aP0, aP1);
            if (ks < 6) asm volatile("s_waitcnt vmcnt(2) lgkmcnt(0)" ::: "memory");
            else        asm volatile("s_waitcnt vmcnt(0) lgkmcnt(0)" ::: "memory");
            __builtin_amdgcn_s_barrier();
        }
    }

    // ---- epilogue: lane row = lr, lane cols = wn + nn*16 + hi*4 + r ----
    float4 bv4[4], av4[4][4];
#pragma unroll
    for (int nn = 0; nn < 4; ++nn)
        bv4[nn] = *reinterpret_cast<const float4*>(p.bias[ty] + wn + nn * 16 + hi * 4);
#pragma unroll
    for (int v = 0; v < 4; ++v)
        if (v < nv) {
            const float* A = p.av[ty * 4 + v];
#pragma unroll
            for (int nn = 0; nn < 4; ++nn)
                av4[v][nn] = *reinterpret_cast<const float4*>(A + wn + nn * 16 + hi * 4);
        }
    int h0 = (w & 3) * 2;
#pragma unroll
    for (int mm = 0; mm < 4; ++mm) {
        int lrow = wm + mm * 16 + lr;
        int row = m0 + lrow;
        float sv[4][2] = {};
#pragma unroll
        for (int nn = 0; nn < 4; ++nn) {
            float c0 = acc[mm][nn][0] + bv4[nn].x;
            float c1 = acc[mm][nn][1] + bv4[nn].y;
            float c2 = acc[mm][nn][2] + bv4[nn].z;
            float c3 = acc[mm][nn][3] + bv4[nn].w;
            if (row < Nrows) {
                ushort4 o; o.x = f2b(c0); o.y = f2b(c1); o.z = f2b(c2); o.w = f2b(c3);
                *reinterpret_cast<ushort4*>(Hout + (size_t)row * 256 + wn + nn * 16 + hi * 4) = o;
            }
#pragma unroll
            for (int v = 0; v < 4; ++v)
                if (v < nv)
                    sv[v][nn >> 1] += c0 * av4[v][nn].x + c1 * av4[v][nn].y +
                                      c2 * av4[v][nn].z + c3 * av4[v][nn].w;
        }
#pragma unroll
        for (int v = 0; v < 4; ++v)
            if (v < nv) {
#pragma unroll
                for (int hp = 0; hp < 2; ++hp) {
                    float s = sv[v][hp];
                    s += __shfl_xor(s, 16); s += __shfl_xor(s, 32);
                    if (hi == 0) satt[v][lrow][h0 + hp] = s;
                }
            }
    }
    __syncthreads();
    for (int i = t; i < nv * 1024; i += 512) {
        int v = i >> 10, rem = i & 1023, lrow = rem >> 3, hd = rem & 7;
        int g = m0 + lrow;
        if (g < Nrows) p.ov[ty * 4 + v][(size_t)g * 8 + hd] = satt[v][lrow][hd];
    }
}

// ---- fused gather + kmean: 64-dst tile, pipelined gather ----
__global__ __launch_bounds__(512, 4) void k_gather_kmean(
    const int* __restrict__ src, const int* __restrict__ count,
    const int* __restrict__ elist, const unsigned short* __restrict__ Hsrc,
    const float* __restrict__ as_, const float* __restrict__ ad_,
    const unsigned short* __restrict__ Bw, const float* __restrict__ kb,
    const float* __restrict__ v, float* __restrict__ ksum,
    float* __restrict__ gout) {
    __shared__ __align__(16) unsigned short Ar[64 * 256];      // 32 KB, swizzled
    __shared__ __align__(16) unsigned short Bs[2][256 * 32];   // 32 KB
    int t = threadIdx.x, l = t & 63, w = t >> 6;
    int m0 = blockIdx.x * 64;
    int lg = l & 15, gb = l & 48;

    auto stageB = [&](int buf, int k0) {
#pragma unroll
        for (int i = 0; i < 2; ++i) {
            int rowb = w * 32 + i * 16;
            async_copy16(Bw + (size_t)(rowb + (l >> 2)) * 256 + k0 + (l & 3) * 8,
                         &Bs[buf][rowb * 32]);
        }
    };
    stageB(0, 0);   // B loads fly during gather

    // upfront dependent-chain loads for both rounds (2 parallel chains)
    int cnt_[2], s1_[2], s2_[2], ld_[2]; float adh_[2]; bool val_[2];
#pragma unroll
    for (int j = 0; j < 2; ++j) {
        int ld = w * 8 + j * 4 + (l >> 4);
        int d = m0 + ld;
        bool valid = d < NPAR;
        int cnt = 0;
        if (valid) { cnt = count[d]; if (cnt > CAP) cnt = CAP; }
        int e1 = (lg < cnt) ? elist[(size_t)d * CAP + lg] : -1;
        int e2 = (lg + 16 < cnt) ? elist[(size_t)d * CAP + lg + 16] : -1;
        ld_[j] = ld; val_[j] = valid; cnt_[j] = cnt;
        s1_[j] = (e1 >= 0) ? src[e1] : 0;
        s2_[j] = (e2 >= 0) ? src[e2] : 0;
        adh_[j] = valid ? ad_[d * 8 + (lg >> 1)] : 0.f;
    }

    float4 vv0 = *reinterpret_cast<const float4*>(v + lg * 16);
    float4 vv1 = *reinterpret_cast<const float4*>(v + lg * 16 + 4);
    float4 vv2 = *reinterpret_cast<const float4*>(v + lg * 16 + 8);
    float4 vv3 = *reinterpret_cast<const float4*>(v + lg * 16 + 12);
    float vr[16] = { vv0.x, vv0.y, vv0.z, vv0.w, vv1.x, vv1.y, vv1.z, vv1.w,
                     vv2.x, vv2.y, vv2.z, vv2.w, vv3.x, vv3.y, vv3.z, vv3.w };

#pragma unroll
    for (int j = 0; j < 2; ++j) {
        int cnt = cnt_[j], s1 = s1_[j], s2 = s2_[j], ld = ld_[j];
        float adh = adh_[j];
        float ar[16];
#pragma unroll
        for (int k = 0; k < 16; ++k) ar[k] = 0.f;
        float den = 0.f;
        // prefetch edge 0 (safe even when cnt==0: s defaults to 0)
        int sC = __shfl(s1, gb);
        const uint4* hp0 = reinterpret_cast<const uint4*>(Hsrc + (size_t)sC * 256 + lg * 16);
        uint4 hA = hp0[0], hB = hp0[1];
        float asv = as_[sC * 8 + (lg >> 1)];
        for (int i = 0; i < cnt; ++i) {
            int iN = i + 1;
            int sN = (iN < 16) ? __shfl(s1, gb + (iN & 15)) : __shfl(s2, gb + ((iN - 16) & 15));
            const uint4* np = reinterpret_cast<const uint4*>(Hsrc + (size_t)sN * 256 + lg * 16);
            uint4 nA = np[0], nB = np[1];
            float nas = as_[sN * 8 + (lg >> 1)];
            float al = asv + adh;
            al = al > 0.f ? al : 0.2f * al;
            float ex = __expf(al); den += ex;
            unsigned wds[8] = { hA.x, hA.y, hA.z, hA.w, hB.x, hB.y, hB.z, hB.w };
#pragma unroll
            for (int k = 0; k < 8; ++k) {
                ar[k * 2]     += ex * b2f((unsigned short)(wds[k] & 0xffffu));
                ar[k * 2 + 1] += ex * b2f((unsigned short)(wds[k] >> 16));
            }
            hA = nA; hB = nB; asv = nas;
        }
        float inv = 1.f / (den + 1e-16f);
        float gs = 0.f;
        __align__(16) unsigned short ob[16];
#pragma unroll
        for (int k = 0; k < 16; ++k) {
            float r = fmaxf(ar[k] * inv, 0.f);
            gs += r * vr[k];
            ob[k] = f2b(r);
        }
        int u0 = (lg * 2) ^ (ld & 7), u1 = (lg * 2 + 1) ^ (ld & 7);
        *reinterpret_cast<uint4*>(&Ar[ld * 256 + u0 * 8]) = *reinterpret_cast<const uint4*>(ob);
        *reinterpret_cast<uint4*>(&Ar[ld * 256 + u1 * 8]) = *reinterpret_cast<const uint4*>(ob + 8);
        gs += __shfl_xor(gs, 1); gs += __shfl_xor(gs, 2); gs += __shfl_xor(gs, 4); gs += __shfl_xor(gs, 8);
        if (lg == 0 && val_[j]) gout[m0 + ld] = gs;
    }
    __syncthreads();

    // GEMM: A resident in Ar (swizzled), B double-buffered linear
    int wm = (w >> 2) * 32, wn = (w & 3) * 64, lr = l & 15, hi = l >> 4;
    f32x4 acc[2][4] = {};
    int cur = 0;
    for (int ks = 0; ks < 8; ++ks) {
        if (ks < 7) stageB(cur ^ 1, (ks + 1) * 32);
        bf16x8 af[2], bfr[4];
#pragma unroll
        for (int mm = 0; mm < 2; ++mm) {
            int rr = wm + mm * 16 + lr;
            af[mm] = *reinterpret_cast<const bf16x8*>(&Ar[rr * 256 + (((ks * 4 + hi) ^ (rr & 7)) * 8)]);
        }
#pragma unroll
        for (int nn = 0; nn < 4; ++nn)
            bfr[nn] = *reinterpret_cast<const bf16x8*>(&Bs[cur][(wn + nn * 16 + lr) * 32 + hi * 8]);
#pragma unroll
        for (int mm = 0; mm < 2; ++mm)
#pragma unroll
            for (int nn = 0; nn < 4; ++nn)
                acc[mm][nn] = __builtin_amdgcn_mfma_f32_16x16x32_bf16(af[mm], bfr[nn], acc[mm][nn], 0, 0, 0);
        __syncthreads();
        cur ^= 1;
    }
#pragma unroll
    for (int nn = 0; nn < 4; ++nn) {
        int col = wn + nn * 16 + lr;
        float kbv = kb[col];
        float cs = 0.f;
#pragma unroll
        for (int mm = 0; mm < 2; ++mm)
#pragma unroll
            for (int r = 0; r < 4; ++r) {
                int row = m0 + wm + mm * 16 + hi * 4 + r;
                if (row < NPAR) cs += fast_tanh(acc[mm][nn][r] + kbv);
            }
        cs += __shfl_xor(cs, 16);
        cs += __shfl_xor(cs, 32);
        if (hi == 0) atomicAdd(&ksum[col], cs);
    }
}

// ---- bucket all 3 metapaths in one launch ----
__global__ void k_bucket3(const int* __restrict__ d0, const int* __restrict__ d1,
                          const int* __restrict__ d2, int* __restrict__ count,
                          int* __restrict__ elist) {
    int b = blockIdx.x;
    int m = b / 782;
    int e = (b - m * 782) * 256 + threadIdx.x;
    if (e >= NEDGE) return;
    const int* dst = m == 0 ? d0 : m == 1 ? d1 : d2;
    int d = dst[e];
    int* cnt = count + (size_t)m * NPAR;
    int* el = elist + (size_t)m * NPAR * CAP;
    int slot = atomicAdd(&cnt[d], 1);
    if (slot < CAP) el[(size_t)d * CAP + slot] = e;
}

// ---- pf phase 1: compact matching edges ----
__global__ void k_pf_scan(const int* __restrict__ psrc, const int* __restrict__ pdst,
                          const int* __restrict__ tgtp, int* __restrict__ mlist) {
    int e = blockIdx.x * 256 + threadIdx.x;
    if (e >= NEDGE) return;
    if (pdst[e] == tgtp[0]) {
        int slot = atomicAdd(&mlist[0], 1);
        if (slot < PFCAP) mlist[1 + slot] = psrc[e];
    }
}

// ---- pf phase 2: wave-parallel accumulate over matches (1 block) ----
__global__ void k_pf_acc(const int* __restrict__ mlist, const int* __restrict__ tgtp,
                         const unsigned short* __restrict__ Hpar,
                         const float* __restrict__ as_pf, const float* __restrict__ ad_pf,
                         float* __restrict__ smallb) {
    __shared__ float sacc[4][256];
    __shared__ float sden[4][8];
    int t = threadIdx.x, w = t >> 6, l = t & 63;
    int tgt = tgtp[0];
    int cnt = mlist[0]; if (cnt > PFCAP) cnt = PFCAP;
    int h = l >> 3;
    float adh = ad_pf[tgt * 8 + h];
    float a0 = 0.f, a1 = 0.f, a2 = 0.f, a3 = 0.f, den = 0.f;
    for (int i = w; i < cnt; i += 4) {
        int s = mlist[1 + i];
        float al = as_pf[s * 8 + h] + adh;
        al = al > 0.f ? al : 0.2f * al;
        float ex = __expf(al);
        ushort4 hv = *reinterpret_cast<const ushort4*>(&Hpar[(size_t)s * 256 + l * 4]);
        a0 += ex * b2f(hv.x); a1 += ex * b2f(hv.y); a2 += ex * b2f(hv.z); a3 += ex * b2f(hv.w);
        den += ex;
    }
    sacc[w][l * 4 + 0] = a0; sacc[w][l * 4 + 1] = a1;
    sacc[w][l * 4 + 2] = a2; sacc[w][l * 4 + 3] = a3;
    if ((l & 7) == 0) sden[w][h] = den;
    __syncthreads();
    smallb[t] = sacc[0][t] + sacc[1][t] + sacc[2][t] + sacc[3][t];
    if (t < 8) smallb[256 + t] = sden[0][t] + sden[1][t] + sden[2][t] + sden[3][t];
}

// ---- semantic attention softmax + scalar C ----
__global__ void k_finalize(const float* __restrict__ kacc, const float* __restrict__ q,
                           const float* __restrict__ u, float* __restrict__ smallb) {
    __shared__ float red[256];
    __shared__ float sm[3];
    int t = threadIdx.x;
    float qv = q[t];
    for (int m = 0; m < 3; ++m) {
        red[t] = kacc[m * 256 + t] * qv;
        __syncthreads();
        for (int s = 128; s > 0; s >>= 1) { if (t < s) red[t] += red[t + s]; __syncthreads(); }
        if (t == 0) sm[m] = red[0] / (float)NPAR;
        __syncthreads();
    }
    float den = smallb[256 + (t >> 5)];
    float rt = fmaxf(smallb[t] / (den + 1e-16f), 0.f);
    red[t] = rt * u[t];
    __syncthreads();
    for (int s = 128; s > 0; s >>= 1) { if (t < s) red[t] += red[t + s]; __syncthreads(); }
    if (t == 0) {
        float mx = fmaxf(sm[0], fmaxf(sm[1], sm[2]));
        float e0 = expf(sm[0] - mx), e1 = expf(sm[1] - mx), e2 = expf(sm[2] - mx);
        float sd = e0 + e1 + e2;
        smallb[265] = e0 / sd; smallb[266] = e1 / sd; smallb[267] = e2 / sd;
        smallb[268] = red[0] + smallb[264];
    }
}

// ---- final scores ----
__global__ void k_scores(const float* __restrict__ g, const float* __restrict__ smallb,
                         float* __restrict__ out) {
    int i = blockIdx.x * 256 + threadIdx.x;
    if (i >= NPAR) return;
    out[i] = smallb[268] + smallb[265] * g[i] + smallb[266] * g[NPAR + i] + smallb[267] * g[2 * NPAR + i];
}

extern "C" void kernel_launch(void* const* d_in, const int* in_sizes, int n_in,
                              void* d_out, int out_size, void* d_ws, size_t ws_size,
                              hipStream_t stream) {
    char* base = (char*)d_ws;
    size_t off = 0;
    auto alloc = [&](size_t b) -> void* { void* p = base + off; off += (b + 255) & ~(size_t)255; return p; };

    unsigned short* h_par = (unsigned short*)alloc((size_t)MPAD * 256 * 2);
    unsigned short* h_fig = (unsigned short*)alloc((size_t)NFIG * 256 * 2);
    unsigned short* h_tab = (unsigned short*)alloc((size_t)NTAB * 256 * 2);
    unsigned short* h_cit = (unsigned short*)alloc((size_t)NCIT * 256 * 2);
    unsigned short* WTall = (unsigned short*)alloc((size_t)5 * 65536 * 2);
    unsigned short* WT_par = WTall, *WT_fig = WTall + 65536, *WT_tab = WTall + 2 * 65536,
                  *WT_cit = WTall + 3 * 65536, *kwT = WTall + 4 * 65536;
    float* as_pf = (float*)alloc((size_t)NPAR * 8 * 4);
    float* ad_fp = (float*)alloc((size_t)NPAR * 8 * 4);
    float* ad_tp = (float*)alloc((size_t)NPAR * 8 * 4);
    float* ad_cp = (float*)alloc((size_t)NPAR * 8 * 4);
    float* as_fp = (float*)alloc((size_t)NFIG * 8 * 4);
    float* ad_pf = (float*)alloc((size_t)NFIG * 8 * 4);
    float* as_tp = (float*)alloc((size_t)NTAB * 8 * 4);
    float* as_cp = (float*)alloc((size_t)NCIT * 8 * 4);
    float* gbuf  = (float*)alloc((size_t)3 * NPAR * 4);
    int* count3  = (int*)alloc((size_t)3 * NPAR * 4);
    int* elist3  = (int*)alloc((size_t)3 * NPAR * CAP * 4);
    float* kacc  = (float*)alloc(3 * 256 * 4);
    float* smallb = (float*)alloc(512 * 4);
    int* mlist   = (int*)alloc((1 + PFCAP) * 4);
    float* uvec  = (float*)alloc(256 * 4);
    float* vvec  = (float*)alloc(256 * 4);

    hipMemsetAsync(kacc, 0, 5632, stream);
    hipMemsetAsync(count3, 0, (size_t)3 * NPAR * 4, stream);

    k_transpose5<<<5 * 256, 256, 0, stream>>>((const float*)d_in[4], (const float*)d_in[6],
                                              (const float*)d_in[8], (const float*)d_in[10],
                                              (const float*)d_in[24], WTall);

    k_precompute<<<1, 256, 0, stream>>>((const float*)d_in[29], (const float*)d_in[30],
                                        (const float*)d_in[27], (const float*)d_in[28],
                                        (const float*)d_in[35], (const float*)d_in[36],
                                        uvec, vvec, smallb);

    k_bucket3<<<3 * 782, 256, 0, stream>>>((const int*)d_in[40], (const int*)d_in[44],
                                           (const int*)d_in[48], count3, elist3);
    k_pf_scan<<<782, 256, 0, stream>>>((const int*)d_in[37], (const int*)d_in[38],
                                       (const int*)d_in[49], mlist);

    ProjPack pp;
    pp.X[0] = (const float*)d_in[0]; pp.X[1] = (const float*)d_in[1];
    pp.X[2] = (const float*)d_in[2]; pp.X[3] = (const float*)d_in[3];
    pp.WT[0] = WT_par; pp.WT[1] = WT_fig; pp.WT[2] = WT_tab; pp.WT[3] = WT_cit;
    pp.bias[0] = (const float*)d_in[5]; pp.bias[1] = (const float*)d_in[7];
    pp.bias[2] = (const float*)d_in[9]; pp.bias[3] = (const float*)d_in[11];
    pp.H[0] = h_par; pp.H[1] = h_fig; pp.H[2] = h_tab; pp.H[3] = h_cit;
    pp.nrows[0] = NPAR; pp.nrows[1] = NFIG; pp.nrows[2] = NTAB; pp.nrows[3] = NCIT;
    pp.bbase[0] = 0; pp.bbase[1] = 782; pp.bbase[2] = 939; pp.bbase[3] = 1096;
    pp.nv[0] = 4; pp.nv[1] = 2; pp.nv[2] = 1; pp.nv[3] = 1;
    for (int i = 0; i < 16; ++i) { pp.av[i] = nullptr; pp.ov[i] = nullptr; }
    pp.av[0] = (const float*)d_in[12]; pp.ov[0] = as_pf;   // par
    pp.av[1] = (const float*)d_in[15]; pp.ov[1] = ad_fp;
    pp.av[2] = (const float*)d_in[19]; pp.ov[2] = ad_tp;
    pp.av[3] = (const float*)d_in[23]; pp.ov[3] = ad_cp;
    pp.av[4] = (const float*)d_in[14]; pp.ov[4] = as_fp;   // fig
    pp.av[5] = (const float*)d_in[13]; pp.ov[5] = ad_pf;
    pp.av[8] = (const float*)d_in[18]; pp.ov[8] = as_tp;   // tab
    pp.av[12] = (const float*)d_in[22]; pp.ov[12] = as_cp; // cit
    k_gemm_proj<<<1487, 512, 0, stream>>>(pp);

    k_pf_acc<<<1, 256, 0, stream>>>(mlist, (const int*)d_in[49], h_par, as_pf, ad_pf, smallb);

    const int* srcs[3] = { (const int*)d_in[39], (const int*)d_in[43], (const int*)d_in[47] };
    const unsigned short* hsrcs[3] = { h_fig, h_tab, h_cit };
    const float* ass[3] = { as_fp, as_tp, as_cp };
    const float* ads[3] = { ad_fp, ad_tp, ad_cp };
    for (int m = 0; m < 3; ++m) {
        k_gather_kmean<<<1563, 512, 0, stream>>>(srcs[m], count3 + (size_t)m * NPAR,
                                                 elist3 + (size_t)m * NPAR * CAP, hsrcs[m],
                                                 ass[m], ads[m], kwT, (const float*)d_in[25],
                                                 vvec, kacc + m * 256, gbuf + (size_t)m * NPAR);
    }

    k_finalize<<<1, 256, 0, stream>>>(kacc, (const float*)d_in[26], uvec, smallb);
    k_scores<<<391, 256, 0, stream>>>(gbuf, smallb, (float*)d_out);
}

// Round 8
// 361.825 us; speedup vs baseline: 1.7623x; 1.3742x over previous
//
#include <hip/hip_runtime.h>
#include <hip/hip_bf16.h>
#include <math.h>

typedef float f32x4 __attribute__((ext_vector_type(4)));
typedef short bf16x8 __attribute__((ext_vector_type(8)));

#define NPAR 100000
#define NFIG 20000
#define NTAB 20000
#define NCIT 50000
#define NEDGE 200000
#define CAP 32
#define MPAD 100096
#define PFCAP 79

__device__ __forceinline__ unsigned short f2b(float f) {
    union { float f; unsigned u; } x; x.f = f;
    unsigned r = x.u + 0x7FFFu + ((x.u >> 16) & 1u);
    return (unsigned short)(r >> 16);
}
__device__ __forceinline__ float b2f(unsigned short b) {
    union { unsigned u; float f; } x; x.u = ((unsigned)b) << 16; return x.f;
}
__device__ __forceinline__ float fast_tanh(float x) {
    float e = __expf(2.f * x);
    return 1.f - 2.f * __builtin_amdgcn_rcpf(e + 1.f);
}
__device__ __forceinline__ void async_copy16(const unsigned short* g, unsigned short* l) {
    __builtin_amdgcn_global_load_lds(
        (const __attribute__((address_space(1))) unsigned int*)g,
        (__attribute__((address_space(3))) unsigned int*)l, 16, 0, 0);
}

// ---- 5 weight transposes in one launch ----
__global__ void k_transpose5(const float* __restrict__ W0, const float* __restrict__ W1,
                             const float* __restrict__ W2, const float* __restrict__ W3,
                             const float* __restrict__ W4, unsigned short* __restrict__ WT) {
    int b = blockIdx.x, which = b >> 8, k = b & 255, n = threadIdx.x;
    const float* W = which == 0 ? W0 : which == 1 ? W1 : which == 2 ? W2 : which == 3 ? W3 : W4;
    WT[(size_t)which * 65536 + n * 256 + k] = f2b(W[k * 256 + n]);
}

// ---- u = Wh_fig @ cls_w1, v = Wh_par @ cls_w2, Cpart ----
__global__ void k_precompute(const float* __restrict__ WhF, const float* __restrict__ bhF,
                             const float* __restrict__ WhP, const float* __restrict__ bhP,
                             const float* __restrict__ clsw, const float* __restrict__ clsb,
                             float* __restrict__ u, float* __restrict__ v, float* __restrict__ smallb) {
    int t = threadIdx.x;
    float su = 0.f, sv = 0.f;
    for (int j = 0; j < 128; ++j) {
        su += WhF[t * 128 + j] * clsw[j];
        sv += WhP[t * 128 + j] * clsw[128 + j];
    }
    u[t] = su; v[t] = sv;
    if (t == 0) {
        float c = clsb[0];
        for (int j = 0; j < 128; ++j) c += bhF[j] * clsw[j] + bhP[j] * clsw[128 + j];
        smallb[264] = c;
    }
}

// ---- merged projection GEMM: swapped MFMA, counted-vmcnt pipeline, fused att;
//      par-type H is NOT stored (dead except 79 rows recomputed by k_pf_proj) ----
struct ProjPack {
    const float* X[4];
    const unsigned short* WT[4];
    const float* bias[4];
    unsigned short* H[4];
    const float* av[16];
    float* ov[16];
    int nrows[4];
    int bbase[4];
    int nv[4];
};

#define LOADA(k0, A0, A1) do { \
    const float4* _p = reinterpret_cast<const float4*>(Arow + (k0)); \
    A0 = _p[0]; A1 = _p[1]; } while (0)
#define WRITEA(buf, A0, A1) do { \
    __align__(16) unsigned short _t[8]; \
    _t[0] = f2b(A0.x); _t[1] = f2b(A0.y); _t[2] = f2b(A0.z); _t[3] = f2b(A0.w); \
    _t[4] = f2b(A1.x); _t[5] = f2b(A1.y); _t[6] = f2b(A1.z); _t[7] = f2b(A1.w); \
    *reinterpret_cast<uint4*>(&As[buf][arow * 32 + acol]) = *reinterpret_cast<const uint4*>(_t); } while (0)

__global__ __launch_bounds__(512, 4) void k_gemm_proj(ProjPack p) {
    __shared__ __align__(16) unsigned short As[2][128 * 32];   // 16 KB
    __shared__ __align__(16) unsigned short Bs[2][256 * 32];   // 32 KB
    __shared__ float satt[4][128][8];                          // 16 KB
    int bid = blockIdx.x;
    int ty = (bid >= p.bbase[1]) + (bid >= p.bbase[2]) + (bid >= p.bbase[3]);
    int m0 = (bid - p.bbase[ty]) * 128;
    const float* Xf = p.X[ty];
    const unsigned short* B = p.WT[ty];
    unsigned short* Hout = p.H[ty];
    int Nrows = p.nrows[ty];
    int nv = p.nv[ty];

    int t = threadIdx.x, l = t & 63, w = t >> 6;
    int wm = (w >> 2) * 64, wn = (w & 3) * 64;
    int lr = l & 15, hi = l >> 4;
    int arow = t >> 2, acol = (t & 3) * 8;
    int arow_c = m0 + arow; if (arow_c > Nrows - 1) arow_c = Nrows - 1;
    const float* Arow = Xf + (size_t)arow_c * 256 + acol;
    f32x4 acc[4][4] = {};
    float4 aP0, aP1, aQ0, aQ1;

    auto stageB = [&](int buf, int k0) {
#pragma unroll
        for (int i = 0; i < 2; ++i) {
            int rowb = w * 32 + i * 16;
            async_copy16(B + (size_t)(rowb + (l >> 2)) * 256 + k0 + (l & 3) * 8,
                         &Bs[buf][rowb * 32]);
        }
    };

    LOADA(0, aP0, aP1);
    stageB(0, 0);
    WRITEA(0, aP0, aP1);
    LOADA(32, aQ0, aQ1);
    asm volatile("s_waitcnt vmcnt(2) lgkmcnt(0)" ::: "memory");
    __builtin_amdgcn_s_barrier();

#pragma unroll
    for (int ks = 0; ks < 8; ++ks) {
        int cur = ks & 1;
        if (ks < 7) stageB(cur ^ 1, (ks + 1) * 32);
        if (ks < 6) {
            if ((ks & 1) == 0) LOADA((ks + 2) * 32, aP0, aP1);
            else               LOADA((ks + 2) * 32, aQ0, aQ1);
        }
        bf16x8 af[4], bfr[4];
#pragma unroll
        for (int mm = 0; mm < 4; ++mm)
            af[mm] = *reinterpret_cast<const bf16x8*>(&As[cur][(wm + mm * 16 + lr) * 32 + hi * 8]);
#pragma unroll
        for (int nn = 0; nn < 4; ++nn)
            bfr[nn] = *reinterpret_cast<const bf16x8*>(&Bs[cur][(wn + nn * 16 + lr) * 32 + hi * 8]);
#pragma unroll
        for (int mm = 0; mm < 4; ++mm)
#pragma unroll
            for (int nn = 0; nn < 4; ++nn)   // swapped: D[m=lane&15][n=(lane>>4)*4+reg]
                acc[mm][nn] = __builtin_amdgcn_mfma_f32_16x16x32_bf16(bfr[nn], af[mm], acc[mm][nn], 0, 0, 0);
        if (ks < 7) {
            if ((ks & 1) == 0) WRITEA(cur ^ 1, aQ0, aQ1);
            else               WRITEA(cur ^ 1, aP0, aP1);
            if (ks < 6) asm volatile("s_waitcnt vmcnt(2) lgkmcnt(0)" ::: "memory");
            else        asm volatile("s_waitcnt vmcnt(0) lgkmcnt(0)" ::: "memory");
            __builtin_amdgcn_s_barrier();
        }
    }

    // ---- epilogue ----
    float4 bv4[4], av4[4][4];
#pragma unroll
    for (int nn = 0; nn < 4; ++nn)
        bv4[nn] = *reinterpret_cast<const float4*>(p.bias[ty] + wn + nn * 16 + hi * 4);
#pragma unroll
    for (int v = 0; v < 4; ++v)
        if (v < nv) {
            const float* A = p.av[ty * 4 + v];
#pragma unroll
            for (int nn = 0; nn < 4; ++nn)
                av4[v][nn] = *reinterpret_cast<const float4*>(A + wn + nn * 16 + hi * 4);
        }
    int h0 = (w & 3) * 2;
#pragma unroll
    for (int mm = 0; mm < 4; ++mm) {
        int lrow = wm + mm * 16 + lr;
        int row = m0 + lrow;
        float sv[4][2] = {};
#pragma unroll
        for (int nn = 0; nn < 4; ++nn) {
            float c0 = acc[mm][nn][0] + bv4[nn].x;
            float c1 = acc[mm][nn][1] + bv4[nn].y;
            float c2 = acc[mm][nn][2] + bv4[nn].z;
            float c3 = acc[mm][nn][3] + bv4[nn].w;
            if (ty != 0 && row < Nrows) {
                ushort4 o; o.x = f2b(c0); o.y = f2b(c1); o.z = f2b(c2); o.w = f2b(c3);
                *reinterpret_cast<ushort4*>(Hout + (size_t)row * 256 + wn + nn * 16 + hi * 4) = o;
            }
#pragma unroll
            for (int v = 0; v < 4; ++v)
                if (v < nv)
                    sv[v][nn >> 1] += c0 * av4[v][nn].x + c1 * av4[v][nn].y +
                                      c2 * av4[v][nn].z + c3 * av4[v][nn].w;
        }
#pragma unroll
        for (int v = 0; v < 4; ++v)
            if (v < nv) {
#pragma unroll
                for (int hp = 0; hp < 2; ++hp) {
                    float s = sv[v][hp];
                    s += __shfl_xor(s, 16); s += __shfl_xor(s, 32);
                    if (hi == 0) satt[v][lrow][h0 + hp] = s;
                }
            }
    }
    __syncthreads();
    for (int i = t; i < nv * 1024; i += 512) {
        int v = i >> 10, rem = i & 1023, lrow = rem >> 3, hd = rem & 7;
        int g = m0 + lrow;
        if (g < Nrows) p.ov[ty * 4 + v][(size_t)g * 8 + hd] = satt[v][lrow][hd];
    }
}

// ---- recompute the <=PFCAP par projection rows needed by pf_acc ----
__global__ void k_pf_proj(const int* __restrict__ mlist, const float* __restrict__ Xp,
                          const unsigned short* __restrict__ WTp, const float* __restrict__ bp,
                          unsigned short* __restrict__ Hs) {
    int b = blockIdx.x;
    int cnt = mlist[0]; if (cnt > PFCAP) cnt = PFCAP;
    if (b >= cnt) return;
    int s = mlist[1 + b];
    __shared__ float xr[256];
    int t = threadIdx.x;
    xr[t] = Xp[(size_t)s * 256 + t];
    __syncthreads();
    const unsigned short* wrow = WTp + (size_t)t * 256;
    float acc = bp[t];
    for (int k = 0; k < 256; k += 8) {
        uint4 wv = *reinterpret_cast<const uint4*>(wrow + k);
        unsigned wsv[4] = { wv.x, wv.y, wv.z, wv.w };
#pragma unroll
        for (int j = 0; j < 4; ++j) {
            acc += xr[k + j * 2]     * b2f((unsigned short)(wsv[j] & 0xffffu));
            acc += xr[k + j * 2 + 1] * b2f((unsigned short)(wsv[j] >> 16));
        }
    }
    Hs[(size_t)b * 256 + t] = f2b(acc);
}

// ---- fused gather + kmean: 64-dst tile, pipelined gather, 8-way hashed atomics ----
__global__ __launch_bounds__(512, 4) void k_gather_kmean(
    const int* __restrict__ src, const int* __restrict__ count,
    const int* __restrict__ elist, const unsigned short* __restrict__ Hsrc,
    const float* __restrict__ as_, const float* __restrict__ ad_,
    const unsigned short* __restrict__ Bw, const float* __restrict__ kb,
    const float* __restrict__ v, float* __restrict__ ksum,
    float* __restrict__ gout) {
    __shared__ __align__(16) unsigned short Ar[64 * 256];      // 32 KB, swizzled
    __shared__ __align__(16) unsigned short Bs[2][256 * 32];   // 32 KB
    int t = threadIdx.x, l = t & 63, w = t >> 6;
    int m0 = blockIdx.x * 64;
    int lg = l & 15, gb = l & 48;
    float* ks_rep = ksum + (size_t)(blockIdx.x & 7) * 256;

    auto stageB = [&](int buf, int k0) {
#pragma unroll
        for (int i = 0; i < 2; ++i) {
            int rowb = w * 32 + i * 16;
            async_copy16(Bw + (size_t)(rowb + (l >> 2)) * 256 + k0 + (l & 3) * 8,
                         &Bs[buf][rowb * 32]);
        }
    };
    stageB(0, 0);   // B loads fly during gather

    int cnt_[2], s1_[2], s2_[2], ld_[2]; float adh_[2]; bool val_[2];
#pragma unroll
    for (int j = 0; j < 2; ++j) {
        int ld = w * 8 + j * 4 + (l >> 4);
        int d = m0 + ld;
        bool valid = d < NPAR;
        int cnt = 0;
        if (valid) { cnt = count[d]; if (cnt > CAP) cnt = CAP; }
        int e1 = (lg < cnt) ? elist[(size_t)d * CAP + lg] : -1;
        int e2 = (lg + 16 < cnt) ? elist[(size_t)d * CAP + lg + 16] : -1;
        ld_[j] = ld; val_[j] = valid; cnt_[j] = cnt;
        s1_[j] = (e1 >= 0) ? src[e1] : 0;
        s2_[j] = (e2 >= 0) ? src[e2] : 0;
        adh_[j] = valid ? ad_[d * 8 + (lg >> 1)] : 0.f;
    }

    float4 vv0 = *reinterpret_cast<const float4*>(v + lg * 16);
    float4 vv1 = *reinterpret_cast<const float4*>(v + lg * 16 + 4);
    float4 vv2 = *reinterpret_cast<const float4*>(v + lg * 16 + 8);
    float4 vv3 = *reinterpret_cast<const float4*>(v + lg * 16 + 12);
    float vr[16] = { vv0.x, vv0.y, vv0.z, vv0.w, vv1.x, vv1.y, vv1.z, vv1.w,
                     vv2.x, vv2.y, vv2.z, vv2.w, vv3.x, vv3.y, vv3.z, vv3.w };

#pragma unroll
    for (int j = 0; j < 2; ++j) {
        int cnt = cnt_[j], s1 = s1_[j], s2 = s2_[j], ld = ld_[j];
        float adh = adh_[j];
        float ar[16];
#pragma unroll
        for (int k = 0; k < 16; ++k) ar[k] = 0.f;
        float den = 0.f;
        int sC = __shfl(s1, gb);
        const uint4* hp0 = reinterpret_cast<const uint4*>(Hsrc + (size_t)sC * 256 + lg * 16);
        uint4 hA = {}, hB = {};
        float asv = 0.f;
        if (cnt > 0) { hA = hp0[0]; hB = hp0[1]; asv = as_[sC * 8 + (lg >> 1)]; }
        for (int i = 0; i < cnt; ++i) {
            int iN = i + 1;
            uint4 nA = {}, nB = {};
            float nas = 0.f;
            if (iN < cnt) {
                int sN = (iN < 16) ? __shfl(s1, gb + (iN & 15)) : __shfl(s2, gb + ((iN - 16) & 15));
                const uint4* np = reinterpret_cast<const uint4*>(Hsrc + (size_t)sN * 256 + lg * 16);
                nA = np[0]; nB = np[1];
                nas = as_[sN * 8 + (lg >> 1)];
            }
            float al = asv + adh;
            al = al > 0.f ? al : 0.2f * al;
            float ex = __expf(al); den += ex;
            unsigned wds[8] = { hA.x, hA.y, hA.z, hA.w, hB.x, hB.y, hB.z, hB.w };
#pragma unroll
            for (int k = 0; k < 8; ++k) {
                ar[k * 2]     += ex * b2f((unsigned short)(wds[k] & 0xffffu));
                ar[k * 2 + 1] += ex * b2f((unsigned short)(wds[k] >> 16));
            }
            hA = nA; hB = nB; asv = nas;
        }
        float inv = 1.f / (den + 1e-16f);
        float gs = 0.f;
        __align__(16) unsigned short ob[16];
#pragma unroll
        for (int k = 0; k < 16; ++k) {
            float r = fmaxf(ar[k] * inv, 0.f);
            gs += r * vr[k];
            ob[k] = f2b(r);
        }
        int u0 = (lg * 2) ^ (ld & 7), u1 = (lg * 2 + 1) ^ (ld & 7);
        *reinterpret_cast<uint4*>(&Ar[ld * 256 + u0 * 8]) = *reinterpret_cast<const uint4*>(ob);
        *reinterpret_cast<uint4*>(&Ar[ld * 256 + u1 * 8]) = *reinterpret_cast<const uint4*>(ob + 8);
        gs += __shfl_xor(gs, 1); gs += __shfl_xor(gs, 2); gs += __shfl_xor(gs, 4); gs += __shfl_xor(gs, 8);
        if (lg == 0 && val_[j]) gout[m0 + ld] = gs;
    }
    __syncthreads();

    // GEMM: A resident in Ar (swizzled), B double-buffered linear
    int wm = (w >> 2) * 32, wn = (w & 3) * 64, lr = l & 15, hi = l >> 4;
    f32x4 acc[2][4] = {};
    int cur = 0;
    for (int ks = 0; ks < 8; ++ks) {
        if (ks < 7) stageB(cur ^ 1, (ks + 1) * 32);
        bf16x8 af[2], bfr[4];
#pragma unroll
        for (int mm = 0; mm < 2; ++mm) {
            int rr = wm + mm * 16 + lr;
            af[mm] = *reinterpret_cast<const bf16x8*>(&Ar[rr * 256 + (((ks * 4 + hi) ^ (rr & 7)) * 8)]);
        }
#pragma unroll
        for (int nn = 0; nn < 4; ++nn)
            bfr[nn] = *reinterpret_cast<const bf16x8*>(&Bs[cur][(wn + nn * 16 + lr) * 32 + hi * 8]);
#pragma unroll
        for (int mm = 0; mm < 2; ++mm)
#pragma unroll
            for (int nn = 0; nn < 4; ++nn)
                acc[mm][nn] = __builtin_amdgcn_mfma_f32_16x16x32_bf16(af[mm], bfr[nn], acc[mm][nn], 0, 0, 0);
        __syncthreads();
        cur ^= 1;
    }
#pragma unroll
    for (int nn = 0; nn < 4; ++nn) {
        int col = wn + nn * 16 + lr;
        float kbv = kb[col];
        float cs = 0.f;
#pragma unroll
        for (int mm = 0; mm < 2; ++mm)
#pragma unroll
            for (int r = 0; r < 4; ++r) {
                int row = m0 + wm + mm * 16 + hi * 4 + r;
                if (row < NPAR) cs += fast_tanh(acc[mm][nn][r] + kbv);
            }
        cs += __shfl_xor(cs, 16);
        cs += __shfl_xor(cs, 32);
        if (hi == 0) atomicAdd(&ks_rep[col], cs);
    }
}

// ---- bucket all 3 metapaths in one launch ----
__global__ void k_bucket3(const int* __restrict__ d0, const int* __restrict__ d1,
                          const int* __restrict__ d2, int* __restrict__ count,
                          int* __restrict__ elist) {
    int b = blockIdx.x;
    int m = b / 782;
    int e = (b - m * 782) * 256 + threadIdx.x;
    if (e >= NEDGE) return;
    const int* dst = m == 0 ? d0 : m == 1 ? d1 : d2;
    int d = dst[e];
    int* cnt = count + (size_t)m * NPAR;
    int* el = elist + (size_t)m * NPAR * CAP;
    int slot = atomicAdd(&cnt[d], 1);
    if (slot < CAP) el[(size_t)d * CAP + slot] = e;
}

// ---- pf phase 1: compact matching edges ----
__global__ void k_pf_scan(const int* __restrict__ psrc, const int* __restrict__ pdst,
                          const int* __restrict__ tgtp, int* __restrict__ mlist) {
    int e = blockIdx.x * 256 + threadIdx.x;
    if (e >= NEDGE) return;
    if (pdst[e] == tgtp[0]) {
        int slot = atomicAdd(&mlist[0], 1);
        if (slot < PFCAP) mlist[1 + slot] = psrc[e];
    }
}

// ---- pf phase 2: wave-parallel accumulate over matches (1 block) ----
__global__ void k_pf_acc(const int* __restrict__ mlist, const int* __restrict__ tgtp,
                         const unsigned short* __restrict__ Hs,
                         const float* __restrict__ as_pf, const float* __restrict__ ad_pf,
                         float* __restrict__ smallb) {
    __shared__ float sacc[4][256];
    __shared__ float sden[4][8];
    int t = threadIdx.x, w = t >> 6, l = t & 63;
    int tgt = tgtp[0];
    int cnt = mlist[0]; if (cnt > PFCAP) cnt = PFCAP;
    int h = l >> 3;
    float adh = ad_pf[tgt * 8 + h];
    float a0 = 0.f, a1 = 0.f, a2 = 0.f, a3 = 0.f, den = 0.f;
    for (int i = w; i < cnt; i += 4) {
        int s = mlist[1 + i];
        float al = as_pf[s * 8 + h] + adh;
        al = al > 0.f ? al : 0.2f * al;
        float ex = __expf(al);
        ushort4 hv = *reinterpret_cast<const ushort4*>(&Hs[(size_t)i * 256 + l * 4]);
        a0 += ex * b2f(hv.x); a1 += ex * b2f(hv.y); a2 += ex * b2f(hv.z); a3 += ex * b2f(hv.w);
        den += ex;
    }
    sacc[w][l * 4 + 0] = a0; sacc[w][l * 4 + 1] = a1;
    sacc[w][l * 4 + 2] = a2; sacc[w][l * 4 + 3] = a3;
    if ((l & 7) == 0) sden[w][h] = den;
    __syncthreads();
    smallb[t] = sacc[0][t] + sacc[1][t] + sacc[2][t] + sacc[3][t];
    if (t < 8) smallb[256 + t] = sden[0][t] + sden[1][t] + sden[2][t] + sden[3][t];
}

// ---- semantic attention softmax + scalar C (sums 8 kacc replicas) ----
__global__ void k_finalize(const float* __restrict__ kacc, const float* __restrict__ q,
                           const float* __restrict__ u, float* __restrict__ smallb) {
    __shared__ float red[256];
    __shared__ float sm[3];
    int t = threadIdx.x;
    float qv = q[t];
    for (int m = 0; m < 3; ++m) {
        float acc = 0.f;
#pragma unroll
        for (int rep = 0; rep < 8; ++rep) acc += kacc[m * 2048 + rep * 256 + t];
        red[t] = acc * qv;
        __syncthreads();
        for (int s = 128; s > 0; s >>= 1) { if (t < s) red[t] += red[t + s]; __syncthreads(); }
        if (t == 0) sm[m] = red[0] / (float)NPAR;
        __syncthreads();
    }
    float den = smallb[256 + (t >> 5)];
    float rt = fmaxf(smallb[t] / (den + 1e-16f), 0.f);
    red[t] = rt * u[t];
    __syncthreads();
    for (int s = 128; s > 0; s >>= 1) { if (t < s) red[t] += red[t + s]; __syncthreads(); }
    if (t == 0) {
        float mx = fmaxf(sm[0], fmaxf(sm[1], sm[2]));
        float e0 = expf(sm[0] - mx), e1 = expf(sm[1] - mx), e2 = expf(sm[2] - mx);
        float sd = e0 + e1 + e2;
        smallb[265] = e0 / sd; smallb[266] = e1 / sd; smallb[267] = e2 / sd;
        smallb[268] = red[0] + smallb[264];
    }
}

// ---- final scores ----
__global__ void k_scores(const float* __restrict__ g, const float* __restrict__ smallb,
                         float* __restrict__ out) {
    int i = blockIdx.x * 256 + threadIdx.x;
    if (i >= NPAR) return;
    out[i] = smallb[268] + smallb[265] * g[i] + smallb[266] * g[NPAR + i] + smallb[267] * g[2 * NPAR + i];
}

extern "C" void kernel_launch(void* const* d_in, const int* in_sizes, int n_in,
                              void* d_out, int out_size, void* d_ws, size_t ws_size,
                              hipStream_t stream) {
    char* base = (char*)d_ws;
    size_t off = 0;
    auto alloc = [&](size_t b) -> void* { void* p = base + off; off += (b + 255) & ~(size_t)255; return p; };

    unsigned short* Hsmall = (unsigned short*)alloc((size_t)PFCAP * 256 * 2);
    unsigned short* h_fig = (unsigned short*)alloc((size_t)NFIG * 256 * 2);
    unsigned short* h_tab = (unsigned short*)alloc((size_t)NTAB * 256 * 2);
    unsigned short* h_cit = (unsigned short*)alloc((size_t)NCIT * 256 * 2);
    unsigned short* WTall = (unsigned short*)alloc((size_t)5 * 65536 * 2);
    unsigned short* WT_par = WTall, *WT_fig = WTall + 65536, *WT_tab = WTall + 2 * 65536,
                  *WT_cit = WTall + 3 * 65536, *kwT = WTall + 4 * 65536;
    float* as_pf = (float*)alloc((size_t)NPAR * 8 * 4);
    float* ad_fp = (float*)alloc((size_t)NPAR * 8 * 4);
    float* ad_tp = (float*)alloc((size_t)NPAR * 8 * 4);
    float* ad_cp = (float*)alloc((size_t)NPAR * 8 * 4);
    float* as_fp = (float*)alloc((size_t)NFIG * 8 * 4);
    float* ad_pf = (float*)alloc((size_t)NFIG * 8 * 4);
    float* as_tp = (float*)alloc((size_t)NTAB * 8 * 4);
    float* as_cp = (float*)alloc((size_t)NCIT * 8 * 4);
    float* gbuf  = (float*)alloc((size_t)3 * NPAR * 4);
    int* count3  = (int*)alloc((size_t)3 * NPAR * 4);
    int* elist3  = (int*)alloc((size_t)3 * NPAR * CAP * 4);
    float* kacc  = (float*)alloc((size_t)3 * 8 * 256 * 4);   // [3][8][256] replicas
    float* smallb = (float*)alloc(512 * 4);
    int* mlist   = (int*)alloc((1 + PFCAP) * 4);
    float* uvec  = (float*)alloc(256 * 4);
    float* vvec  = (float*)alloc(256 * 4);

    // memset covers kacc(24576) + smallb(2048) + mlist(512 padded) contiguous
    hipMemsetAsync(kacc, 0, 24576 + 2048 + 512, stream);
    hipMemsetAsync(count3, 0, (size_t)3 * NPAR * 4, stream);

    k_transpose5<<<5 * 256, 256, 0, stream>>>((const float*)d_in[4], (const float*)d_in[6],
                                              (const float*)d_in[8], (const float*)d_in[10],
                                              (const float*)d_in[24], WTall);

    k_precompute<<<1, 256, 0, stream>>>((const float*)d_in[29], (const float*)d_in[30],
                                        (const float*)d_in[27], (const float*)d_in[28],
                                        (const float*)d_in[35], (const float*)d_in[36],
                                        uvec, vvec, smallb);

    k_bucket3<<<3 * 782, 256, 0, stream>>>((const int*)d_in[40], (const int*)d_in[44],
                                           (const int*)d_in[48], count3, elist3);
    k_pf_scan<<<782, 256, 0, stream>>>((const int*)d_in[37], (const int*)d_in[38],
                                       (const int*)d_in[49], mlist);
    k_pf_proj<<<PFCAP, 256, 0, stream>>>(mlist, (const float*)d_in[0], WT_par,
                                         (const float*)d_in[5], Hsmall);

    ProjPack pp;
    pp.X[0] = (const float*)d_in[0]; pp.X[1] = (const float*)d_in[1];
    pp.X[2] = (const float*)d_in[2]; pp.X[3] = (const float*)d_in[3];
    pp.WT[0] = WT_par; pp.WT[1] = WT_fig; pp.WT[2] = WT_tab; pp.WT[3] = WT_cit;
    pp.bias[0] = (const float*)d_in[5]; pp.bias[1] = (const float*)d_in[7];
    pp.bias[2] = (const float*)d_in[9]; pp.bias[3] = (const float*)d_in[11];
    pp.H[0] = h_fig; pp.H[1] = h_fig; pp.H[2] = h_tab; pp.H[3] = h_cit;  // H[0] never stored
    pp.nrows[0] = NPAR; pp.nrows[1] = NFIG; pp.nrows[2] = NTAB; pp.nrows[3] = NCIT;
    pp.bbase[0] = 0; pp.bbase[1] = 782; pp.bbase[2] = 939; pp.bbase[3] = 1096;
    pp.nv[0] = 4; pp.nv[1] = 2; pp.nv[2] = 1; pp.nv[3] = 1;
    for (int i = 0; i < 16; ++i) { pp.av[i] = nullptr; pp.ov[i] = nullptr; }
    pp.av[0] = (const float*)d_in[12]; pp.ov[0] = as_pf;   // par
    pp.av[1] = (const float*)d_in[15]; pp.ov[1] = ad_fp;
    pp.av[2] = (const float*)d_in[19]; pp.ov[2] = ad_tp;
    pp.av[3] = (const float*)d_in[23]; pp.ov[3] = ad_cp;
    pp.av[4] = (const float*)d_in[14]; pp.ov[4] = as_fp;   // fig
    pp.av[5] = (const float*)d_in[13]; pp.ov[5] = ad_pf;
    pp.av[8] = (const float*)d_in[18]; pp.ov[8] = as_tp;   // tab
    pp.av[12] = (const float*)d_in[22]; pp.ov[12] = as_cp; // cit
    k_gemm_proj<<<1487, 512, 0, stream>>>(pp);

    k_pf_acc<<<1, 256, 0, stream>>>(mlist, (const int*)d_in[49], Hsmall, as_pf, ad_pf, smallb);

    const int* srcs[3] = { (const int*)d_in[39], (const int*)d_in[43], (const int*)d_in[47] };
    const unsigned short* hsrcs[3] = { h_fig, h_tab, h_cit };
    const float* ass[3] = { as_fp, as_tp, as_cp };
    const float* ads[3] = { ad_fp, ad_tp, ad_cp };
    for (int m = 0; m < 3; ++m) {
        k_gather_kmean<<<1563, 512, 0, stream>>>(srcs[m], count3 + (size_t)m * NPAR,
                                                 elist3 + (size_t)m * NPAR * CAP, hsrcs[m],
                                                 ass[m], ads[m], kwT, (const float*)d_in[25],
                                                 vvec, kacc + (size_t)m * 2048,
                                                 gbuf + (size_t)m * NPAR);
    }

    k_finalize<<<1, 256, 0, stream>>>(kacc, (const float*)d_in[26], uvec, smallb);
    k_scores<<<391, 256, 0, stream>>>(gbuf, smallb, (float*)d_out);
}